// Round 1
// baseline (10979.997 us; speedup 1.0000x reference)
//
#include <hip/hip_runtime.h>
#include <hip/hip_bf16.h>
#include <math.h>

#define NN   50000
#define EE   800000
#define DDIM 128
#define RREL 16
#define LLAY 5
#define HHID 512

// ---------------- build x0 = [obj_emb[objs] | attr_emb[attributes]] ----------------
__global__ void build_x0_kernel(const int* __restrict__ objs, const int* __restrict__ attrs,
                                const float* __restrict__ obj_emb, const float* __restrict__ attr_emb,
                                float* __restrict__ x0) {
  int t = blockIdx.x * blockDim.x + threadIdx.x;
  if (t >= NN * 32) return;
  int n = t >> 5, q = t & 31;
  float4 v;
  if (q < 24) v = *(const float4*)&obj_emb[(size_t)objs[n] * 96 + q * 4];
  else        v = *(const float4*)&attr_emb[(size_t)attrs[n] * 32 + (q - 24) * 4];
  *(float4*)&x0[(size_t)n * 128 + q * 4] = v;
}

// ---------------- count: cnt[o*R+p]++, hist[p]++ ----------------
__global__ void count_kernel(const int* __restrict__ triples, int* __restrict__ cnt,
                             int* __restrict__ hist) {
  __shared__ int lh[RREL];
  if (threadIdx.x < RREL) lh[threadIdx.x] = 0;
  __syncthreads();
  int e = blockIdx.x * blockDim.x + threadIdx.x;
  if (e < EE) {
    int p = triples[e * 3 + 1];
    int o = triples[e * 3 + 2];
    atomicAdd(&cnt[o * RREL + p], 1);
    atomicAdd(&lh[p], 1);
  }
  __syncthreads();
  if (threadIdx.x < RREL) atomicAdd(&hist[threadIdx.x], lh[threadIdx.x]);
}

// ---------------- exclusive scan of 16 bins ----------------
__global__ void scan_kernel(const int* __restrict__ hist, int* __restrict__ binStart) {
  if (threadIdx.x == 0 && blockIdx.x == 0) {
    int s = 0;
    for (int r = 0; r < RREL; ++r) { binStart[r] = s; s += hist[r]; }
    binStart[RREL] = s;
  }
}

// ---------------- counting-sort edges by relation; w = 1/deg ----------------
__global__ void sort_kernel(const int* __restrict__ triples, const int* __restrict__ cnt,
                            const int* __restrict__ binStart, int* __restrict__ cursor,
                            int* __restrict__ sS, int* __restrict__ oS, float* __restrict__ wS) {
  __shared__ int lh[RREL], lbase[RREL];
  if (threadIdx.x < RREL) lh[threadIdx.x] = 0;
  __syncthreads();
  int e = blockIdx.x * blockDim.x + threadIdx.x;
  int p = 0, s = 0, o = 0, my = 0;
  bool valid = (e < EE);
  if (valid) {
    s = triples[e * 3 + 0]; p = triples[e * 3 + 1]; o = triples[e * 3 + 2];
    my = atomicAdd(&lh[p], 1);
  }
  __syncthreads();
  if (threadIdx.x < RREL) lbase[threadIdx.x] = atomicAdd(&cursor[threadIdx.x], lh[threadIdx.x]);
  __syncthreads();
  if (valid) {
    int pos = binStart[p] + lbase[p] + my;
    sS[pos] = s; oS[pos] = o;
    int c = cnt[o * RREL + p];
    wS[pos] = 1.0f / (float)(c > 0 ? c : 1);
  }
}

// ---------------- root GEMM: y = x @ W (128x128) + bias ----------------
__global__ __launch_bounds__(256) void root_gemm(const float* __restrict__ x,
                                                 const float* __restrict__ W,
                                                 const float* __restrict__ bias,
                                                 float* __restrict__ y) {
  __shared__ float xs[64][32];
  __shared__ float ws[32][128];
  const int tid = threadIdx.x;
  const int oc = tid & 31;
  const int eg = tid >> 5;
  const int row0 = blockIdx.x * 64;
  float acc[8][4];
#pragma unroll
  for (int e = 0; e < 8; ++e) { acc[e][0] = 0.f; acc[e][1] = 0.f; acc[e][2] = 0.f; acc[e][3] = 0.f; }

  for (int k0 = 0; k0 < 128; k0 += 32) {
#pragma unroll
    for (int i = 0; i < 4; ++i) {
      int idx = (tid + i * 256) * 4;
      int kk = idx >> 7, ff = idx & 127;
      *(float4*)&ws[kk][ff] = *(const float4*)&W[(size_t)(k0 + kk) * 128 + ff];
    }
#pragma unroll
    for (int i = 0; i < 8; ++i) {
      int idx = tid + i * 256;
      int rr = idx >> 5, kk = idx & 31;
      int n = row0 + rr;
      xs[rr][kk] = (n < NN) ? x[(size_t)n * 128 + k0 + kk] : 0.f;
    }
    __syncthreads();
#pragma unroll
    for (int kk = 0; kk < 32; kk += 4) {
      float4 w0 = *(float4*)&ws[kk + 0][oc * 4];
      float4 w1 = *(float4*)&ws[kk + 1][oc * 4];
      float4 w2 = *(float4*)&ws[kk + 2][oc * 4];
      float4 w3 = *(float4*)&ws[kk + 3][oc * 4];
#pragma unroll
      for (int e = 0; e < 8; ++e) {
        float4 xq = *(float4*)&xs[eg * 8 + e][kk];
        acc[e][0] += xq.x * w0.x + xq.y * w1.x + xq.z * w2.x + xq.w * w3.x;
        acc[e][1] += xq.x * w0.y + xq.y * w1.y + xq.z * w2.y + xq.w * w3.y;
        acc[e][2] += xq.x * w0.z + xq.y * w1.z + xq.z * w2.z + xq.w * w3.z;
        acc[e][3] += xq.x * w0.w + xq.y * w1.w + xq.z * w2.w + xq.w * w3.w;
      }
    }
    __syncthreads();
  }
  float4 bb = *(const float4*)&bias[oc * 4];
#pragma unroll
  for (int e = 0; e < 8; ++e) {
    int n = row0 + eg * 8 + e;
    if (n < NN) {
      float4 v;
      v.x = acc[e][0] + bb.x; v.y = acc[e][1] + bb.y;
      v.z = acc[e][2] + bb.z; v.w = acc[e][3] + bb.w;
      *(float4*)&y[(size_t)n * 128 + oc * 4] = v;
    }
  }
}

// ---------------- edge GEMM per relation: y[o] += (x[s] @ W_r) * w ----------------
__global__ __launch_bounds__(256) void edge_gemm(const float* __restrict__ x,
                                                 float* __restrict__ y,
                                                 const float* __restrict__ Wl,    // (R,128,128)
                                                 const int* __restrict__ sS,
                                                 const int* __restrict__ oS,
                                                 const float* __restrict__ wS,
                                                 const int* __restrict__ binStart) {
  const int r = blockIdx.y;
  const float* W = Wl + (size_t)r * 128 * 128;
  const int eBeg = binStart[r], eEnd = binStart[r + 1];
  __shared__ float xs[64][32];
  __shared__ float ws[32][128];
  __shared__ int   ss[64];
  const int tid = threadIdx.x;
  const int oc = tid & 31;
  const int eg = tid >> 5;

  for (int t0 = eBeg + blockIdx.x * 64; t0 < eEnd; t0 += gridDim.x * 64) {
    const int nE = min(64, eEnd - t0);
    if (tid < 64) ss[tid] = (tid < nE) ? sS[t0 + tid] : -1;
    float acc[8][4];
#pragma unroll
    for (int e = 0; e < 8; ++e) { acc[e][0] = 0.f; acc[e][1] = 0.f; acc[e][2] = 0.f; acc[e][3] = 0.f; }

    for (int k0 = 0; k0 < 128; k0 += 32) {
      __syncthreads();   // ss visible (1st iter) / prev compute done (later iters)
#pragma unroll
      for (int i = 0; i < 4; ++i) {
        int idx = (tid + i * 256) * 4;
        int kk = idx >> 7, ff = idx & 127;
        *(float4*)&ws[kk][ff] = *(const float4*)&W[(size_t)(k0 + kk) * 128 + ff];
      }
#pragma unroll
      for (int i = 0; i < 8; ++i) {
        int idx = tid + i * 256;
        int rr = idx >> 5, kk = idx & 31;
        int sn = ss[rr];
        xs[rr][kk] = (sn >= 0) ? x[(size_t)sn * 128 + k0 + kk] : 0.f;
      }
      __syncthreads();
#pragma unroll
      for (int kk = 0; kk < 32; kk += 4) {
        float4 w0 = *(float4*)&ws[kk + 0][oc * 4];
        float4 w1 = *(float4*)&ws[kk + 1][oc * 4];
        float4 w2 = *(float4*)&ws[kk + 2][oc * 4];
        float4 w3 = *(float4*)&ws[kk + 3][oc * 4];
#pragma unroll
        for (int e = 0; e < 8; ++e) {
          float4 xq = *(float4*)&xs[eg * 8 + e][kk];
          acc[e][0] += xq.x * w0.x + xq.y * w1.x + xq.z * w2.x + xq.w * w3.x;
          acc[e][1] += xq.x * w0.y + xq.y * w1.y + xq.z * w2.y + xq.w * w3.y;
          acc[e][2] += xq.x * w0.z + xq.y * w1.z + xq.z * w2.z + xq.w * w3.z;
          acc[e][3] += xq.x * w0.w + xq.y * w1.w + xq.z * w2.w + xq.w * w3.w;
        }
      }
    }
    __syncthreads();   // compute done before ss/xs/ws restage next tile
#pragma unroll
    for (int e = 0; e < 8; ++e) {
      int idx = eg * 8 + e;
      if (idx < nE) {
        int on = oS[t0 + idx];
        float wgt = wS[t0 + idx];
        float* yp = &y[(size_t)on * 128 + oc * 4];
        atomicAdd(yp + 0, acc[e][0] * wgt);
        atomicAdd(yp + 1, acc[e][1] * wgt);
        atomicAdd(yp + 2, acc[e][2] * wgt);
        atomicAdd(yp + 3, acc[e][3] * wgt);
      }
    }
  }
}

// ---------------- relu in place ----------------
__global__ void relu_kernel(float* __restrict__ x, int n4) {
  int t = blockIdx.x * blockDim.x + threadIdx.x;
  if (t >= n4) return;
  float4 v = *(float4*)&x[(size_t)t * 4];
  v.x = fmaxf(v.x, 0.f); v.y = fmaxf(v.y, 0.f);
  v.z = fmaxf(v.z, 0.f); v.w = fmaxf(v.w, 0.f);
  *(float4*)&x[(size_t)t * 4] = v;
}

// ---------------- MLP layer-1 GEMM: H = relu([xfin|z|attr] @ W1 + b1) ----------------
__global__ __launch_bounds__(256) void mlp_gemm(const float* __restrict__ xfin,
                                                const float* __restrict__ z,
                                                const float* __restrict__ attr_emb,
                                                const int* __restrict__ attrs,
                                                const float* __restrict__ W1,   // (K,512)
                                                const float* __restrict__ b1,
                                                float* __restrict__ H, int K) {
  __shared__ float xs[64][32];
  __shared__ float ws[32][128];
  const int tid = threadIdx.x;
  const int oc = tid & 31;
  const int eg = tid >> 5;
  const int row0 = blockIdx.x * 64;
  const int hb = blockIdx.y * 128;
  float acc[8][4];
#pragma unroll
  for (int e = 0; e < 8; ++e) { acc[e][0] = 0.f; acc[e][1] = 0.f; acc[e][2] = 0.f; acc[e][3] = 0.f; }

  for (int k0 = 0; k0 < K; k0 += 32) {
#pragma unroll
    for (int i = 0; i < 4; ++i) {
      int idx = (tid + i * 256) * 4;
      int kk = idx >> 7, ff = idx & 127;
      *(float4*)&ws[kk][ff] = *(const float4*)&W1[(size_t)(k0 + kk) * 512 + hb + ff];
    }
#pragma unroll
    for (int i = 0; i < 8; ++i) {
      int idx = tid + i * 256;
      int rr = idx >> 5, kk = idx & 31;
      int n = row0 + rr;
      int k = k0 + kk;
      float v = 0.f;
      if (n < NN) {
        if (k < 128)      v = xfin[(size_t)n * 128 + k];
        else if (k < 256) v = z[(size_t)n * 128 + (k - 128)];
        else              v = attr_emb[(size_t)attrs[n] * 32 + (k - 256)];
      }
      xs[rr][kk] = v;
    }
    __syncthreads();
#pragma unroll
    for (int kk = 0; kk < 32; kk += 4) {
      float4 w0 = *(float4*)&ws[kk + 0][oc * 4];
      float4 w1 = *(float4*)&ws[kk + 1][oc * 4];
      float4 w2 = *(float4*)&ws[kk + 2][oc * 4];
      float4 w3 = *(float4*)&ws[kk + 3][oc * 4];
#pragma unroll
      for (int e = 0; e < 8; ++e) {
        float4 xq = *(float4*)&xs[eg * 8 + e][kk];
        acc[e][0] += xq.x * w0.x + xq.y * w1.x + xq.z * w2.x + xq.w * w3.x;
        acc[e][1] += xq.x * w0.y + xq.y * w1.y + xq.z * w2.y + xq.w * w3.y;
        acc[e][2] += xq.x * w0.z + xq.y * w1.z + xq.z * w2.z + xq.w * w3.z;
        acc[e][3] += xq.x * w0.w + xq.y * w1.w + xq.z * w2.w + xq.w * w3.w;
      }
    }
    __syncthreads();
  }
  float4 bb = *(const float4*)&b1[hb + oc * 4];
#pragma unroll
  for (int e = 0; e < 8; ++e) {
    int n = row0 + eg * 8 + e;
    if (n < NN) {
      float4 v;
      v.x = fmaxf(acc[e][0] + bb.x, 0.f); v.y = fmaxf(acc[e][1] + bb.y, 0.f);
      v.z = fmaxf(acc[e][2] + bb.z, 0.f); v.w = fmaxf(acc[e][3] + bb.w, 0.f);
      *(float4*)&H[(size_t)n * 512 + hb + oc * 4] = v;
    }
  }
}

// ---------------- boxes: out = H @ W2(512x6) + b2 ----------------
__global__ __launch_bounds__(256) void box_out_kernel(const float* __restrict__ H,
                                                      const float* __restrict__ W2,
                                                      const float* __restrict__ b2,
                                                      float* __restrict__ out) {
  __shared__ float w2s[512 * 6];
  for (int i = threadIdx.x; i < 512 * 6; i += 256) w2s[i] = W2[i];
  __syncthreads();
  int wid = threadIdx.x >> 6, lane = threadIdx.x & 63;
  int n = blockIdx.x * 4 + wid;
  if (n >= NN) return;
  float a[6] = {0.f, 0.f, 0.f, 0.f, 0.f, 0.f};
#pragma unroll
  for (int j = 0; j < 8; ++j) {
    int h = j * 64 + lane;
    float hv = H[(size_t)n * 512 + h];
#pragma unroll
    for (int c = 0; c < 6; ++c) a[c] += hv * w2s[h * 6 + c];
  }
#pragma unroll
  for (int m = 32; m > 0; m >>= 1) {
#pragma unroll
    for (int c = 0; c < 6; ++c) a[c] += __shfl_xor(a[c], m, 64);
  }
  if (lane == 0) {
    out[(size_t)n * 6 + 0] = a[0] + b2[0];
    out[(size_t)n * 6 + 1] = a[1] + b2[1];
    out[(size_t)n * 6 + 2] = a[2] + b2[2];
    out[(size_t)n * 6 + 3] = a[3] + b2[3];
    out[(size_t)n * 6 + 4] = a[4] + b2[4];
    out[(size_t)n * 6 + 5] = a[5] + b2[5];
  }
}

// ---------------- angles: out = log_softmax(H @ W2(512x24) + b2) ----------------
__global__ __launch_bounds__(256) void ang_out_kernel(const float* __restrict__ H,
                                                      const float* __restrict__ W2,
                                                      const float* __restrict__ b2,
                                                      float* __restrict__ out) {
  __shared__ float w2s[512][25];
  __shared__ float b2s[24];
  for (int i = threadIdx.x; i < 512 * 24; i += 256) {
    int h = i / 24, c = i % 24;
    w2s[h][c] = W2[i];
  }
  if (threadIdx.x < 24) b2s[threadIdx.x] = b2[threadIdx.x];
  __syncthreads();
  int wid = threadIdx.x >> 6, lane = threadIdx.x & 63;
  int n = blockIdx.x * 4 + wid;
  if (n >= NN) return;
  float a[24];
#pragma unroll
  for (int c = 0; c < 24; ++c) a[c] = 0.f;
#pragma unroll
  for (int j = 0; j < 8; ++j) {
    int h = j * 64 + lane;
    float hv = H[(size_t)n * 512 + h];
#pragma unroll
    for (int c = 0; c < 24; ++c) a[c] += hv * w2s[h][c];
  }
#pragma unroll
  for (int m = 32; m > 0; m >>= 1) {
#pragma unroll
    for (int c = 0; c < 24; ++c) a[c] += __shfl_xor(a[c], m, 64);
  }
#pragma unroll
  for (int c = 0; c < 24; ++c) a[c] += b2s[c];
  float mx = a[0];
#pragma unroll
  for (int c = 1; c < 24; ++c) mx = fmaxf(mx, a[c]);
  float ssum = 0.f;
#pragma unroll
  for (int c = 0; c < 24; ++c) ssum += expf(a[c] - mx);
  float lse = mx + logf(ssum);
  if (lane == 0) {
#pragma unroll
    for (int c = 0; c < 24; ++c) out[(size_t)n * 24 + c] = a[c] - lse;
  }
}

// ------------------------------------------------------------------------
extern "C" void kernel_launch(void* const* d_in, const int* in_sizes, int n_in,
                              void* d_out, int out_size, void* d_ws, size_t ws_size,
                              hipStream_t stream) {
  const float* z        = (const float*)d_in[0];
  const int*   objs     = (const int*)d_in[1];
  const int*   triples  = (const int*)d_in[2];
  const int*   attrs    = (const int*)d_in[3];
  const float* obj_emb  = (const float*)d_in[4];
  const float* attr_emb = (const float*)d_in[5];
  const float* Wrel     = (const float*)d_in[6];
  const float* Wroot    = (const float*)d_in[7];
  const float* bconv    = (const float*)d_in[8];
  const float* box_W1   = (const float*)d_in[9];
  const float* box_b1   = (const float*)d_in[10];
  const float* box_W2   = (const float*)d_in[11];
  const float* box_b2   = (const float*)d_in[12];
  const float* ang_W1   = (const float*)d_in[13];
  const float* ang_b1   = (const float*)d_in[14];
  const float* ang_W2   = (const float*)d_in[15];
  const float* ang_b2   = (const float*)d_in[16];
  float* out = (float*)d_out;

  // workspace layout
  float* x0   = (float*)d_ws;                         // N*128
  float* x1   = x0 + (size_t)NN * 128;                // N*128
  float* Hbuf = x1 + (size_t)NN * 128;                // N*512
  int*   cnt  = (int*)(Hbuf + (size_t)NN * 512);      // N*R
  int*   sS   = cnt + (size_t)NN * RREL;              // E
  int*   oS   = sS + EE;                              // E
  float* wS   = (float*)(oS + EE);                    // E
  int*   meta = (int*)(wS + EE);                      // 64 ints
  int* hist     = meta;        // 16
  int* binStart = meta + 16;   // 17
  int* cursor   = meta + 40;   // 16

  hipMemsetAsync(cnt, 0, (size_t)NN * RREL * sizeof(int), stream);
  hipMemsetAsync(meta, 0, 64 * sizeof(int), stream);

  build_x0_kernel<<<(NN * 32 + 255) / 256, 256, 0, stream>>>(objs, attrs, obj_emb, attr_emb, x0);
  count_kernel<<<(EE + 255) / 256, 256, 0, stream>>>(triples, cnt, hist);
  scan_kernel<<<1, 64, 0, stream>>>(hist, binStart);
  sort_kernel<<<(EE + 255) / 256, 256, 0, stream>>>(triples, cnt, binStart, cursor, sS, oS, wS);

  float* xc = x0;
  float* xn = x1;
  const int rowBlocks = (NN + 63) / 64;   // 782
  for (int j = 0; j < LLAY; ++j) {
    root_gemm<<<rowBlocks, 256, 0, stream>>>(xc, Wroot + (size_t)j * 128 * 128,
                                             bconv + (size_t)j * 128, xn);
    edge_gemm<<<dim3(256, RREL), 256, 0, stream>>>(xc, xn, Wrel + (size_t)j * RREL * 128 * 128,
                                                   sS, oS, wS, binStart);
    relu_kernel<<<(NN * 32 + 255) / 256, 256, 0, stream>>>(xn, NN * 32);
    float* tmp = xc; xc = xn; xn = tmp;
  }

  // box head
  mlp_gemm<<<dim3(rowBlocks, 4), 256, 0, stream>>>(xc, z, attr_emb, attrs, box_W1, box_b1, Hbuf, 288);
  box_out_kernel<<<(NN + 3) / 4, 256, 0, stream>>>(Hbuf, box_W2, box_b2, out);

  // angle head
  mlp_gemm<<<dim3(rowBlocks, 4), 256, 0, stream>>>(xc, z, attr_emb, attrs, ang_W1, ang_b1, Hbuf, 256);
  ang_out_kernel<<<(NN + 3) / 4, 256, 0, stream>>>(Hbuf, ang_W2, ang_b2, out + (size_t)NN * 6);
}

// Round 2
// 3235.818 us; speedup vs baseline: 3.3933x; 3.3933x over previous
//
#include <hip/hip_runtime.h>
#include <hip/hip_bf16.h>
#include <math.h>

#define NN   50000
#define EE   800000
#define RREL 16
#define LLAY 5
#define NBINS (NN * RREL)

typedef __attribute__((ext_vector_type(8))) short s8v;
typedef __attribute__((ext_vector_type(4))) float f4v;

__device__ __forceinline__ unsigned short f2bf(float f) {
  __hip_bfloat16 h = __float2bfloat16(f);
  return __builtin_bit_cast(unsigned short, h);
}
__device__ __forceinline__ float bf2f(unsigned int u) {
  return __builtin_bit_cast(float, u << 16);
}

// ---------------- build x0 = [obj_emb[objs] | attr_emb[attributes]] ----------------
__global__ void build_x0_kernel(const int* __restrict__ objs, const int* __restrict__ attrs,
                                const float* __restrict__ obj_emb, const float* __restrict__ attr_emb,
                                float* __restrict__ x0) {
  int t = blockIdx.x * blockDim.x + threadIdx.x;
  if (t >= NN * 32) return;
  int n = t >> 5, q = t & 31;
  float4 v;
  if (q < 24) v = *(const float4*)&obj_emb[(size_t)objs[n] * 96 + q * 4];
  else        v = *(const float4*)&attr_emb[(size_t)attrs[n] * 32 + (q - 24) * 4];
  *(float4*)&x0[(size_t)n * 128 + q * 4] = v;
}

// ---------------- count: cnt[o*R+p]++ ----------------
__global__ void count_kernel(const int* __restrict__ triples, int* __restrict__ cnt) {
  int e = blockIdx.x * 256 + threadIdx.x;
  if (e >= EE) return;
  int p = triples[e * 3 + 1], o = triples[e * 3 + 2];
  atomicAdd(&cnt[o * RREL + p], 1);
}

// ---------------- 2-level exclusive scan over NBINS ----------------
__global__ void scanA(const int* __restrict__ cnt, int* __restrict__ binStart,
                      int* __restrict__ partial) {
  __shared__ int buf[1024];
  int g = blockIdx.x * 1024 + threadIdx.x;
  int v = (g < NBINS) ? cnt[g] : 0;
  buf[threadIdx.x] = v;
  __syncthreads();
  for (int d = 1; d < 1024; d <<= 1) {
    int t = (threadIdx.x >= d) ? buf[threadIdx.x - d] : 0;
    __syncthreads();
    buf[threadIdx.x] += t;
    __syncthreads();
  }
  if (g < NBINS) binStart[g] = buf[threadIdx.x] - v;
  if (threadIdx.x == 1023) partial[blockIdx.x] = buf[1023];
}
__global__ void scanB(int* __restrict__ partial, int* __restrict__ binStart, int nPart) {
  __shared__ int buf[1024];
  int v = (threadIdx.x < nPart) ? partial[threadIdx.x] : 0;
  buf[threadIdx.x] = v;
  __syncthreads();
  for (int d = 1; d < 1024; d <<= 1) {
    int t = (threadIdx.x >= d) ? buf[threadIdx.x - d] : 0;
    __syncthreads();
    buf[threadIdx.x] += t;
    __syncthreads();
  }
  if (threadIdx.x < nPart) partial[threadIdx.x] = buf[threadIdx.x] - v;
  if (threadIdx.x == 1023) binStart[NBINS] = buf[1023];
}
__global__ void scanC(int* __restrict__ binStart, const int* __restrict__ partial) {
  int g = blockIdx.x * 1024 + threadIdx.x;
  if (g < NBINS) binStart[g] += partial[blockIdx.x];
}

// ---------------- place edges into (o,p)-sorted order ----------------
__global__ void place_kernel(const int* __restrict__ triples, const int* __restrict__ cnt,
                             const int* __restrict__ binStart, int* __restrict__ cursor,
                             int* __restrict__ offD, float* __restrict__ wD) {
  int e = blockIdx.x * 256 + threadIdx.x;
  if (e >= EE) return;
  int s = triples[e * 3 + 0], p = triples[e * 3 + 1], o = triples[e * 3 + 2];
  int bin = o * RREL + p;
  int pos = binStart[bin] + atomicAdd(&cursor[bin], 1);
  offD[pos] = s * 1024 + (p & 7) * 128;   // element offset into group-H (N,1024) bf16
  wD[pos] = 1.0f / (float)cnt[bin];
}

// ---------------- pre-transpose + bf16-split weights: (L,R,k,f) -> (L,R,f,k) hi/lo ----------------
__global__ void prep_w(const float* __restrict__ Wrel, unsigned short* __restrict__ WThi,
                       unsigned short* __restrict__ WTlo) {
  int t = blockIdx.x * 256 + threadIdx.x;
  if (t >= LLAY * RREL * 128 * 128) return;
  int f = t & 127, k = (t >> 7) & 127, lr = t >> 14;
  float v = Wrel[((size_t)lr * 128 + k) * 128 + f];
  __hip_bfloat16 h = __float2bfloat16(v);
  float hf = __bfloat162float(h);
  __hip_bfloat16 l = __float2bfloat16(v - hf);
  size_t di = ((size_t)lr * 128 + f) * 128 + k;
  WThi[di] = __builtin_bit_cast(unsigned short, h);
  WTlo[di] = __builtin_bit_cast(unsigned short, l);
}

// ---------------- split activations fp32 -> bf16 hi/lo ----------------
__global__ void split_bf16(const float* __restrict__ x, unsigned short* __restrict__ hi,
                           unsigned short* __restrict__ lo, int n4) {
  int t = blockIdx.x * 256 + threadIdx.x;
  if (t >= n4) return;
  float4 v = *(const float4*)&x[(size_t)t * 4];
  ushort4 h, l;
  {
    __hip_bfloat16 hb = __float2bfloat16(v.x); float hf = __bfloat162float(hb);
    h.x = __builtin_bit_cast(unsigned short, hb);
    __hip_bfloat16 lb = __float2bfloat16(v.x - hf); l.x = __builtin_bit_cast(unsigned short, lb);
  }
  {
    __hip_bfloat16 hb = __float2bfloat16(v.y); float hf = __bfloat162float(hb);
    h.y = __builtin_bit_cast(unsigned short, hb);
    __hip_bfloat16 lb = __float2bfloat16(v.y - hf); l.y = __builtin_bit_cast(unsigned short, lb);
  }
  {
    __hip_bfloat16 hb = __float2bfloat16(v.z); float hf = __bfloat162float(hb);
    h.z = __builtin_bit_cast(unsigned short, hb);
    __hip_bfloat16 lb = __float2bfloat16(v.z - hf); l.z = __builtin_bit_cast(unsigned short, lb);
  }
  {
    __hip_bfloat16 hb = __float2bfloat16(v.w); float hf = __bfloat162float(hb);
    h.w = __builtin_bit_cast(unsigned short, hb);
    __hip_bfloat16 lb = __float2bfloat16(v.w - hf); l.w = __builtin_bit_cast(unsigned short, lb);
  }
  *(ushort4*)&hi[(size_t)t * 4] = h;
  *(ushort4*)&lo[(size_t)t * 4] = l;
}

// ---------------- hrel MFMA: H(N,1024 bf16) = x @ Wrel[group] (split hi/lo, fp32 acc) ----------------
// grid: (16, 782); blockIdx.x: rl=y>>1 (0..7), col-half; blockIdx.y: m-tile of 64 rows
__global__ __launch_bounds__(256) void hrel_mfma(const unsigned short* __restrict__ xhi,
                                                 const unsigned short* __restrict__ xlo,
                                                 const unsigned short* __restrict__ Bh,   // (8rel,128f,128k)
                                                 const unsigned short* __restrict__ Bl,
                                                 unsigned short* __restrict__ H) {
  __shared__ __align__(16) unsigned short As[2][64][136];
  __shared__ __align__(16) unsigned short Bs[2][64][136];
  const int tid = threadIdx.x;
  const int rl = blockIdx.x >> 1;
  const int col0 = (blockIdx.x & 1) * 64;
  const int row0 = blockIdx.y * 64;
  const unsigned short* Wh = Bh + ((size_t)rl * 128 + col0) * 128;
  const unsigned short* Wl = Bl + ((size_t)rl * 128 + col0) * 128;

#pragma unroll
  for (int i = 0; i < 4; ++i) {
    int c = tid + i * 256;        // 0..1023
    int r = c >> 4;               // row/col in tile
    int k8 = (c & 15) * 8;        // k start
    int n = row0 + r;
    if (n < NN) {
      *(s8v*)&As[0][r][k8] = *(const s8v*)&xhi[(size_t)n * 128 + k8];
      *(s8v*)&As[1][r][k8] = *(const s8v*)&xlo[(size_t)n * 128 + k8];
    } else {
      s8v zz = {0, 0, 0, 0, 0, 0, 0, 0};
      *(s8v*)&As[0][r][k8] = zz;
      *(s8v*)&As[1][r][k8] = zz;
    }
    *(s8v*)&Bs[0][r][k8] = *(const s8v*)&Wh[(size_t)r * 128 + k8];
    *(s8v*)&Bs[1][r][k8] = *(const s8v*)&Wl[(size_t)r * 128 + k8];
  }
  __syncthreads();

  const int wid = tid >> 6, lane = tid & 63;
  const int mrow = (wid >> 1) * 32;
  const int ncol = (wid & 1) * 32;
  const int lr = lane & 15, lk = (lane >> 4) * 8;

  f4v acc[2][2] = {};
#pragma unroll
  for (int ks = 0; ks < 4; ++ks) {
    int kb = ks * 32 + lk;
    s8v ah0 = *(s8v*)&As[0][mrow + lr     ][kb];
    s8v ah1 = *(s8v*)&As[0][mrow + 16 + lr][kb];
    s8v al0 = *(s8v*)&As[1][mrow + lr     ][kb];
    s8v al1 = *(s8v*)&As[1][mrow + 16 + lr][kb];
    s8v bh0 = *(s8v*)&Bs[0][ncol + lr     ][kb];
    s8v bh1 = *(s8v*)&Bs[0][ncol + 16 + lr][kb];
    s8v bl0 = *(s8v*)&Bs[1][ncol + lr     ][kb];
    s8v bl1 = *(s8v*)&Bs[1][ncol + 16 + lr][kb];
    acc[0][0] = __builtin_amdgcn_mfma_f32_16x16x32_bf16(ah0, bh0, acc[0][0], 0, 0, 0);
    acc[0][1] = __builtin_amdgcn_mfma_f32_16x16x32_bf16(ah0, bh1, acc[0][1], 0, 0, 0);
    acc[1][0] = __builtin_amdgcn_mfma_f32_16x16x32_bf16(ah1, bh0, acc[1][0], 0, 0, 0);
    acc[1][1] = __builtin_amdgcn_mfma_f32_16x16x32_bf16(ah1, bh1, acc[1][1], 0, 0, 0);
    acc[0][0] = __builtin_amdgcn_mfma_f32_16x16x32_bf16(ah0, bl0, acc[0][0], 0, 0, 0);
    acc[0][1] = __builtin_amdgcn_mfma_f32_16x16x32_bf16(ah0, bl1, acc[0][1], 0, 0, 0);
    acc[1][0] = __builtin_amdgcn_mfma_f32_16x16x32_bf16(ah1, bl0, acc[1][0], 0, 0, 0);
    acc[1][1] = __builtin_amdgcn_mfma_f32_16x16x32_bf16(ah1, bl1, acc[1][1], 0, 0, 0);
    acc[0][0] = __builtin_amdgcn_mfma_f32_16x16x32_bf16(al0, bh0, acc[0][0], 0, 0, 0);
    acc[0][1] = __builtin_amdgcn_mfma_f32_16x16x32_bf16(al0, bh1, acc[0][1], 0, 0, 0);
    acc[1][0] = __builtin_amdgcn_mfma_f32_16x16x32_bf16(al1, bh0, acc[1][0], 0, 0, 0);
    acc[1][1] = __builtin_amdgcn_mfma_f32_16x16x32_bf16(al1, bh1, acc[1][1], 0, 0, 0);
  }

#pragma unroll
  for (int mf = 0; mf < 2; ++mf)
#pragma unroll
    for (int nf = 0; nf < 2; ++nf) {
      f4v v = acc[mf][nf];
      int rbase = row0 + mrow + mf * 16 + (lane >> 4) * 4;
      int cg = rl * 128 + col0 + ncol + nf * 16 + lr;
#pragma unroll
      for (int q = 0; q < 4; ++q) {
        int rr = rbase + q;
        if (rr < NN) H[(size_t)rr * 1024 + cg] = f2bf(v[q]);
      }
    }
}

// ---------------- gather: xn[o] += sum_{edges in group} w * H[s,p]; relu on last ----------------
__global__ __launch_bounds__(256) void gather_kernel(const unsigned short* __restrict__ H,
                                                     const int* __restrict__ binStart,
                                                     const int* __restrict__ offD,
                                                     const float* __restrict__ wD,
                                                     float* __restrict__ xn,
                                                     int g, int doRelu) {
  int wid = threadIdx.x >> 6, lane = threadIdx.x & 63;
  int o = blockIdx.x * 4 + wid;
  if (o >= NN) return;
  int beg = binStart[o * RREL + g * 8];
  int end = binStart[o * RREL + g * 8 + 8];
  float a0 = 0.f, a1 = 0.f, b0 = 0.f, b1 = 0.f;
  int i = beg;
  for (; i + 1 < end; i += 2) {
    int of1 = offD[i], of2 = offD[i + 1];
    float w1 = wD[i], w2 = wD[i + 1];
    unsigned int u1 = *(const unsigned int*)&H[of1 + lane * 2];
    unsigned int u2 = *(const unsigned int*)&H[of2 + lane * 2];
    a0 += w1 * bf2f(u1 & 0xffffu);
    a1 += w1 * bf2f(u1 >> 16);
    b0 += w2 * bf2f(u2 & 0xffffu);
    b1 += w2 * bf2f(u2 >> 16);
  }
  if (i < end) {
    int of1 = offD[i];
    float w1 = wD[i];
    unsigned int u1 = *(const unsigned int*)&H[of1 + lane * 2];
    a0 += w1 * bf2f(u1 & 0xffffu);
    a1 += w1 * bf2f(u1 >> 16);
  }
  a0 += b0; a1 += b1;
  float2 cur = *(float2*)&xn[(size_t)o * 128 + lane * 2];
  cur.x += a0; cur.y += a1;
  if (doRelu) { cur.x = fmaxf(cur.x, 0.f); cur.y = fmaxf(cur.y, 0.f); }
  *(float2*)&xn[(size_t)o * 128 + lane * 2] = cur;
}

// ---------------- root GEMM fp32: y = x @ W (128x128) + bias ----------------
__global__ __launch_bounds__(256) void root_gemm(const float* __restrict__ x,
                                                 const float* __restrict__ W,
                                                 const float* __restrict__ bias,
                                                 float* __restrict__ y) {
  __shared__ float xs[64][32];
  __shared__ float ws[32][128];
  const int tid = threadIdx.x;
  const int oc = tid & 31;
  const int eg = tid >> 5;
  const int row0 = blockIdx.x * 64;
  float acc[8][4];
#pragma unroll
  for (int e = 0; e < 8; ++e) { acc[e][0] = 0.f; acc[e][1] = 0.f; acc[e][2] = 0.f; acc[e][3] = 0.f; }

  for (int k0 = 0; k0 < 128; k0 += 32) {
#pragma unroll
    for (int i = 0; i < 4; ++i) {
      int idx = (tid + i * 256) * 4;
      int kk = idx >> 7, ff = idx & 127;
      *(float4*)&ws[kk][ff] = *(const float4*)&W[(size_t)(k0 + kk) * 128 + ff];
    }
#pragma unroll
    for (int i = 0; i < 8; ++i) {
      int idx = tid + i * 256;
      int rr = idx >> 5, kk = idx & 31;
      int n = row0 + rr;
      xs[rr][kk] = (n < NN) ? x[(size_t)n * 128 + k0 + kk] : 0.f;
    }
    __syncthreads();
#pragma unroll
    for (int kk = 0; kk < 32; kk += 4) {
      float4 w0 = *(float4*)&ws[kk + 0][oc * 4];
      float4 w1 = *(float4*)&ws[kk + 1][oc * 4];
      float4 w2 = *(float4*)&ws[kk + 2][oc * 4];
      float4 w3 = *(float4*)&ws[kk + 3][oc * 4];
#pragma unroll
      for (int e = 0; e < 8; ++e) {
        float4 xq = *(float4*)&xs[eg * 8 + e][kk];
        acc[e][0] += xq.x * w0.x + xq.y * w1.x + xq.z * w2.x + xq.w * w3.x;
        acc[e][1] += xq.x * w0.y + xq.y * w1.y + xq.z * w2.y + xq.w * w3.y;
        acc[e][2] += xq.x * w0.z + xq.y * w1.z + xq.z * w2.z + xq.w * w3.z;
        acc[e][3] += xq.x * w0.w + xq.y * w1.w + xq.z * w2.w + xq.w * w3.w;
      }
    }
    __syncthreads();
  }
  float4 bb = *(const float4*)&bias[oc * 4];
#pragma unroll
  for (int e = 0; e < 8; ++e) {
    int n = row0 + eg * 8 + e;
    if (n < NN) {
      float4 v;
      v.x = acc[e][0] + bb.x; v.y = acc[e][1] + bb.y;
      v.z = acc[e][2] + bb.z; v.w = acc[e][3] + bb.w;
      *(float4*)&y[(size_t)n * 128 + oc * 4] = v;
    }
  }
}

// ---------------- MLP layer-1 GEMM: H = relu([xfin|z|attr] @ W1 + b1) ----------------
__global__ __launch_bounds__(256) void mlp_gemm(const float* __restrict__ xfin,
                                                const float* __restrict__ z,
                                                const float* __restrict__ attr_emb,
                                                const int* __restrict__ attrs,
                                                const float* __restrict__ W1,
                                                const float* __restrict__ b1,
                                                float* __restrict__ H, int K) {
  __shared__ float xs[64][32];
  __shared__ float ws[32][128];
  const int tid = threadIdx.x;
  const int oc = tid & 31;
  const int eg = tid >> 5;
  const int row0 = blockIdx.x * 64;
  const int hb = blockIdx.y * 128;
  float acc[8][4];
#pragma unroll
  for (int e = 0; e < 8; ++e) { acc[e][0] = 0.f; acc[e][1] = 0.f; acc[e][2] = 0.f; acc[e][3] = 0.f; }

  for (int k0 = 0; k0 < K; k0 += 32) {
#pragma unroll
    for (int i = 0; i < 4; ++i) {
      int idx = (tid + i * 256) * 4;
      int kk = idx >> 7, ff = idx & 127;
      *(float4*)&ws[kk][ff] = *(const float4*)&W1[(size_t)(k0 + kk) * 512 + hb + ff];
    }
#pragma unroll
    for (int i = 0; i < 8; ++i) {
      int idx = tid + i * 256;
      int rr = idx >> 5, kk = idx & 31;
      int n = row0 + rr;
      int k = k0 + kk;
      float v = 0.f;
      if (n < NN) {
        if (k < 128)      v = xfin[(size_t)n * 128 + k];
        else if (k < 256) v = z[(size_t)n * 128 + (k - 128)];
        else              v = attr_emb[(size_t)attrs[n] * 32 + (k - 256)];
      }
      xs[rr][kk] = v;
    }
    __syncthreads();
#pragma unroll
    for (int kk = 0; kk < 32; kk += 4) {
      float4 w0 = *(float4*)&ws[kk + 0][oc * 4];
      float4 w1 = *(float4*)&ws[kk + 1][oc * 4];
      float4 w2 = *(float4*)&ws[kk + 2][oc * 4];
      float4 w3 = *(float4*)&ws[kk + 3][oc * 4];
#pragma unroll
      for (int e = 0; e < 8; ++e) {
        float4 xq = *(float4*)&xs[eg * 8 + e][kk];
        acc[e][0] += xq.x * w0.x + xq.y * w1.x + xq.z * w2.x + xq.w * w3.x;
        acc[e][1] += xq.x * w0.y + xq.y * w1.y + xq.z * w2.y + xq.w * w3.y;
        acc[e][2] += xq.x * w0.z + xq.y * w1.z + xq.z * w2.z + xq.w * w3.z;
        acc[e][3] += xq.x * w0.w + xq.y * w1.w + xq.z * w2.w + xq.w * w3.w;
      }
    }
    __syncthreads();
  }
  float4 bb = *(const float4*)&b1[hb + oc * 4];
#pragma unroll
  for (int e = 0; e < 8; ++e) {
    int n = row0 + eg * 8 + e;
    if (n < NN) {
      float4 v;
      v.x = fmaxf(acc[e][0] + bb.x, 0.f); v.y = fmaxf(acc[e][1] + bb.y, 0.f);
      v.z = fmaxf(acc[e][2] + bb.z, 0.f); v.w = fmaxf(acc[e][3] + bb.w, 0.f);
      *(float4*)&H[(size_t)n * 512 + hb + oc * 4] = v;
    }
  }
}

// ---------------- boxes head ----------------
__global__ __launch_bounds__(256) void box_out_kernel(const float* __restrict__ H,
                                                      const float* __restrict__ W2,
                                                      const float* __restrict__ b2,
                                                      float* __restrict__ out) {
  __shared__ float w2s[512 * 6];
  for (int i = threadIdx.x; i < 512 * 6; i += 256) w2s[i] = W2[i];
  __syncthreads();
  int wid = threadIdx.x >> 6, lane = threadIdx.x & 63;
  int n = blockIdx.x * 4 + wid;
  if (n >= NN) return;
  float a[6] = {0.f, 0.f, 0.f, 0.f, 0.f, 0.f};
#pragma unroll
  for (int j = 0; j < 8; ++j) {
    int h = j * 64 + lane;
    float hv = H[(size_t)n * 512 + h];
#pragma unroll
    for (int c = 0; c < 6; ++c) a[c] += hv * w2s[h * 6 + c];
  }
#pragma unroll
  for (int m = 32; m > 0; m >>= 1) {
#pragma unroll
    for (int c = 0; c < 6; ++c) a[c] += __shfl_xor(a[c], m, 64);
  }
  if (lane == 0) {
#pragma unroll
    for (int c = 0; c < 6; ++c) out[(size_t)n * 6 + c] = a[c] + b2[c];
  }
}

// ---------------- angles head ----------------
__global__ __launch_bounds__(256) void ang_out_kernel(const float* __restrict__ H,
                                                      const float* __restrict__ W2,
                                                      const float* __restrict__ b2,
                                                      float* __restrict__ out) {
  __shared__ float w2s[512][25];
  __shared__ float b2s[24];
  for (int i = threadIdx.x; i < 512 * 24; i += 256) {
    int h = i / 24, c = i % 24;
    w2s[h][c] = W2[i];
  }
  if (threadIdx.x < 24) b2s[threadIdx.x] = b2[threadIdx.x];
  __syncthreads();
  int wid = threadIdx.x >> 6, lane = threadIdx.x & 63;
  int n = blockIdx.x * 4 + wid;
  if (n >= NN) return;
  float a[24];
#pragma unroll
  for (int c = 0; c < 24; ++c) a[c] = 0.f;
#pragma unroll
  for (int j = 0; j < 8; ++j) {
    int h = j * 64 + lane;
    float hv = H[(size_t)n * 512 + h];
#pragma unroll
    for (int c = 0; c < 24; ++c) a[c] += hv * w2s[h][c];
  }
#pragma unroll
  for (int m = 32; m > 0; m >>= 1) {
#pragma unroll
    for (int c = 0; c < 24; ++c) a[c] += __shfl_xor(a[c], m, 64);
  }
#pragma unroll
  for (int c = 0; c < 24; ++c) a[c] += b2s[c];
  float mx = a[0];
#pragma unroll
  for (int c = 1; c < 24; ++c) mx = fmaxf(mx, a[c]);
  float ssum = 0.f;
#pragma unroll
  for (int c = 0; c < 24; ++c) ssum += expf(a[c] - mx);
  float lse = mx + logf(ssum);
  if (lane == 0) {
#pragma unroll
    for (int c = 0; c < 24; ++c) out[(size_t)n * 24 + c] = a[c] - lse;
  }
}

// ------------------------------------------------------------------------
extern "C" void kernel_launch(void* const* d_in, const int* in_sizes, int n_in,
                              void* d_out, int out_size, void* d_ws, size_t ws_size,
                              hipStream_t stream) {
  const float* z        = (const float*)d_in[0];
  const int*   objs     = (const int*)d_in[1];
  const int*   triples  = (const int*)d_in[2];
  const int*   attrs    = (const int*)d_in[3];
  const float* obj_emb  = (const float*)d_in[4];
  const float* attr_emb = (const float*)d_in[5];
  const float* Wrel     = (const float*)d_in[6];
  const float* Wroot    = (const float*)d_in[7];
  const float* bconv    = (const float*)d_in[8];
  const float* box_W1   = (const float*)d_in[9];
  const float* box_b1   = (const float*)d_in[10];
  const float* box_W2   = (const float*)d_in[11];
  const float* box_b2   = (const float*)d_in[12];
  const float* ang_W1   = (const float*)d_in[13];
  const float* ang_b1   = (const float*)d_in[14];
  const float* ang_W2   = (const float*)d_in[15];
  const float* ang_b2   = (const float*)d_in[16];
  float* out = (float*)d_out;

  // ---- workspace bump allocator (256B aligned) ----
  char* base = (char*)d_ws;
  size_t cur = 0;
  auto alloc = [&](size_t bytes) -> char* {
    char* p = base + cur;
    cur += (bytes + 255) & ~(size_t)255;
    return p;
  };
  float* x0            = (float*)alloc((size_t)NN * 128 * 4);
  float* x1            = (float*)alloc((size_t)NN * 128 * 4);
  unsigned short* Hb   = (unsigned short*)alloc((size_t)NN * 1024 * 2);  // union w/ MLP hidden (N*512 f32)
  unsigned short* xhi  = (unsigned short*)alloc((size_t)NN * 128 * 2);
  unsigned short* xlo  = (unsigned short*)alloc((size_t)NN * 128 * 2);
  unsigned short* WThi = (unsigned short*)alloc((size_t)LLAY * RREL * 128 * 128 * 2);
  unsigned short* WTlo = (unsigned short*)alloc((size_t)LLAY * RREL * 128 * 128 * 2);
  int*   cnt      = (int*)alloc((size_t)NBINS * 4);
  int*   binStart = (int*)alloc((size_t)(NBINS + 1) * 4);
  int*   cursor   = (int*)alloc((size_t)NBINS * 4);
  int*   partial  = (int*)alloc(4096);
  int*   offD     = (int*)alloc((size_t)EE * 4);
  float* wD       = (float*)alloc((size_t)EE * 4);
  float* Hmlp = (float*)Hb;

  hipMemsetAsync(cnt, 0, (size_t)NBINS * 4, stream);
  hipMemsetAsync(cursor, 0, (size_t)NBINS * 4, stream);

  build_x0_kernel<<<(NN * 32 + 255) / 256, 256, 0, stream>>>(objs, attrs, obj_emb, attr_emb, x0);
  count_kernel<<<(EE + 255) / 256, 256, 0, stream>>>(triples, cnt);
  const int nPart = (NBINS + 1023) / 1024;   // 782
  scanA<<<nPart, 1024, 0, stream>>>(cnt, binStart, partial);
  scanB<<<1, 1024, 0, stream>>>(partial, binStart, nPart);
  scanC<<<nPart, 1024, 0, stream>>>(binStart, partial);
  place_kernel<<<(EE + 255) / 256, 256, 0, stream>>>(triples, cnt, binStart, cursor, offD, wD);
  prep_w<<<(LLAY * RREL * 128 * 128 + 255) / 256, 256, 0, stream>>>(Wrel, WThi, WTlo);

  float* xc = x0;
  float* xn = x1;
  const int rowBlocks = (NN + 63) / 64;   // 782
  for (int j = 0; j < LLAY; ++j) {
    split_bf16<<<(NN * 32 + 255) / 256, 256, 0, stream>>>(xc, xhi, xlo, NN * 32);
    root_gemm<<<rowBlocks, 256, 0, stream>>>(xc, Wroot + (size_t)j * 128 * 128,
                                             bconv + (size_t)j * 128, xn);
    for (int g = 0; g < 2; ++g) {
      const unsigned short* Bh = WThi + ((size_t)j * RREL + g * 8) * 128 * 128;
      const unsigned short* Bl = WTlo + ((size_t)j * RREL + g * 8) * 128 * 128;
      hrel_mfma<<<dim3(16, rowBlocks), 256, 0, stream>>>(xhi, xlo, Bh, Bl, Hb);
      gather_kernel<<<(NN + 3) / 4, 256, 0, stream>>>(Hb, binStart, offD, wD, xn, g, (g == 1) ? 1 : 0);
    }
    float* tmp = xc; xc = xn; xn = tmp;
  }

  // box head
  mlp_gemm<<<dim3(rowBlocks, 4), 256, 0, stream>>>(xc, z, attr_emb, attrs, box_W1, box_b1, Hmlp, 288);
  box_out_kernel<<<(NN + 3) / 4, 256, 0, stream>>>(Hmlp, box_W2, box_b2, out);

  // angle head
  mlp_gemm<<<dim3(rowBlocks, 4), 256, 0, stream>>>(xc, z, attr_emb, attrs, ang_W1, ang_b1, Hmlp, 256);
  ang_out_kernel<<<(NN + 3) / 4, 256, 0, stream>>>(Hmlp, ang_W2, ang_b2, out + (size_t)NN * 6);
}

// Round 3
// 1840.079 us; speedup vs baseline: 5.9671x; 1.7585x over previous
//
#include <hip/hip_runtime.h>
#include <hip/hip_bf16.h>
#include <math.h>

#define NN   50000
#define EE   800000
#define RREL 16
#define LLAY 5
#define NBINS (NN * RREL)

typedef __attribute__((ext_vector_type(8))) short s8v;
typedef __attribute__((ext_vector_type(4))) float f4v;

__device__ __forceinline__ unsigned short f2bf(float f) {
  __hip_bfloat16 h = __float2bfloat16(f);
  return __builtin_bit_cast(unsigned short, h);
}
__device__ __forceinline__ float bf2f(unsigned int u) {
  return __builtin_bit_cast(float, u << 16);
}
__device__ __forceinline__ void split1(float v, unsigned short& h, unsigned short& l) {
  __hip_bfloat16 hb = __float2bfloat16(v);
  float hf = __bfloat162float(hb);
  h = __builtin_bit_cast(unsigned short, hb);
  __hip_bfloat16 lb = __float2bfloat16(v - hf);
  l = __builtin_bit_cast(unsigned short, lb);
}

// ---------------- build x0 (fp32) + hi/lo split ----------------
__global__ void build_x0_kernel(const int* __restrict__ objs, const int* __restrict__ attrs,
                                const float* __restrict__ obj_emb, const float* __restrict__ attr_emb,
                                float* __restrict__ x0, unsigned short* __restrict__ xh,
                                unsigned short* __restrict__ xl) {
  int t = blockIdx.x * blockDim.x + threadIdx.x;
  if (t >= NN * 32) return;
  int n = t >> 5, q = t & 31;
  float4 v;
  if (q < 24) v = *(const float4*)&obj_emb[(size_t)objs[n] * 96 + q * 4];
  else        v = *(const float4*)&attr_emb[(size_t)attrs[n] * 32 + (q - 24) * 4];
  *(float4*)&x0[(size_t)n * 128 + q * 4] = v;
  ushort4 h, l;
  split1(v.x, h.x, l.x); split1(v.y, h.y, l.y);
  split1(v.z, h.z, l.z); split1(v.w, h.w, l.w);
  *(ushort4*)&xh[(size_t)n * 128 + q * 4] = h;
  *(ushort4*)&xl[(size_t)n * 128 + q * 4] = l;
}

// ---------------- split z (N,128) and attr_emb[attrs] (N,32) ----------------
__global__ void prep_zattr(const float* __restrict__ z, const int* __restrict__ attrs,
                           const float* __restrict__ attr_emb,
                           unsigned short* __restrict__ zh, unsigned short* __restrict__ zl,
                           unsigned short* __restrict__ ah, unsigned short* __restrict__ al) {
  int t = blockIdx.x * blockDim.x + threadIdx.x;
  if (t >= NN * 40) return;
  int n = t / 40, q = t % 40;
  float4 v;
  ushort4 h, l;
  if (q < 32) {
    v = *(const float4*)&z[(size_t)n * 128 + q * 4];
    split1(v.x, h.x, l.x); split1(v.y, h.y, l.y);
    split1(v.z, h.z, l.z); split1(v.w, h.w, l.w);
    *(ushort4*)&zh[(size_t)n * 128 + q * 4] = h;
    *(ushort4*)&zl[(size_t)n * 128 + q * 4] = l;
  } else {
    int qq = q - 32;
    v = *(const float4*)&attr_emb[(size_t)attrs[n] * 32 + qq * 4];
    split1(v.x, h.x, l.x); split1(v.y, h.y, l.y);
    split1(v.z, h.z, l.z); split1(v.w, h.w, l.w);
    *(ushort4*)&ah[(size_t)n * 32 + qq * 4] = h;
    *(ushort4*)&al[(size_t)n * 32 + qq * 4] = l;
  }
}

// ---------------- count / scan / place ----------------
__global__ void count_kernel(const int* __restrict__ triples, int* __restrict__ cnt) {
  int e = blockIdx.x * 256 + threadIdx.x;
  if (e >= EE) return;
  int p = triples[e * 3 + 1], o = triples[e * 3 + 2];
  atomicAdd(&cnt[o * RREL + p], 1);
}
__global__ void scanA(const int* __restrict__ cnt, int* __restrict__ binStart,
                      int* __restrict__ partial) {
  __shared__ int buf[1024];
  int g = blockIdx.x * 1024 + threadIdx.x;
  int v = (g < NBINS) ? cnt[g] : 0;
  buf[threadIdx.x] = v;
  __syncthreads();
  for (int d = 1; d < 1024; d <<= 1) {
    int t = (threadIdx.x >= d) ? buf[threadIdx.x - d] : 0;
    __syncthreads();
    buf[threadIdx.x] += t;
    __syncthreads();
  }
  if (g < NBINS) binStart[g] = buf[threadIdx.x] - v;
  if (threadIdx.x == 1023) partial[blockIdx.x] = buf[1023];
}
__global__ void scanB(int* __restrict__ partial, int* __restrict__ binStart, int nPart) {
  __shared__ int buf[1024];
  int v = (threadIdx.x < nPart) ? partial[threadIdx.x] : 0;
  buf[threadIdx.x] = v;
  __syncthreads();
  for (int d = 1; d < 1024; d <<= 1) {
    int t = (threadIdx.x >= d) ? buf[threadIdx.x - d] : 0;
    __syncthreads();
    buf[threadIdx.x] += t;
    __syncthreads();
  }
  if (threadIdx.x < nPart) partial[threadIdx.x] = buf[threadIdx.x] - v;
  if (threadIdx.x == 1023) binStart[NBINS] = buf[1023];
}
__global__ void scanC(int* __restrict__ binStart, const int* __restrict__ partial) {
  int g = blockIdx.x * 1024 + threadIdx.x;
  if (g < NBINS) binStart[g] += partial[blockIdx.x];
}
__global__ void place_kernel(const int* __restrict__ triples, const int* __restrict__ cnt,
                             const int* __restrict__ binStart, int* __restrict__ cursor,
                             int* __restrict__ offD, float* __restrict__ wD) {
  int e = blockIdx.x * 256 + threadIdx.x;
  if (e >= EE) return;
  int s = triples[e * 3 + 0], p = triples[e * 3 + 1], o = triples[e * 3 + 2];
  int bin = o * RREL + p;
  int pos = binStart[bin] + atomicAdd(&cursor[bin], 1);
  offD[pos] = s * 1024 + (p & 7) * 128;
  wD[pos] = 1.0f / (float)cnt[bin];
}

// ---------------- weight preps (transpose + hi/lo split) ----------------
__global__ void prep_wrel(const float* __restrict__ Wrel, unsigned short* __restrict__ WThi,
                          unsigned short* __restrict__ WTlo) {
  int t = blockIdx.x * 256 + threadIdx.x;
  if (t >= LLAY * RREL * 128 * 128) return;
  int f = t & 127, k = (t >> 7) & 127, lr = t >> 14;
  float v = Wrel[((size_t)lr * 128 + k) * 128 + f];
  size_t di = ((size_t)lr * 128 + f) * 128 + k;
  split1(v, WThi[di], WTlo[di]);
}
__global__ void prep_wroot(const float* __restrict__ Wroot, unsigned short* __restrict__ hi,
                           unsigned short* __restrict__ lo) {
  int t = blockIdx.x * 256 + threadIdx.x;
  if (t >= LLAY * 128 * 128) return;
  int f = t & 127, k = (t >> 7) & 127, l = t >> 14;
  float v = Wroot[((size_t)l * 128 + k) * 128 + f];
  size_t di = ((size_t)l * 128 + f) * 128 + k;
  split1(v, hi[di], lo[di]);
}
// Wcat (1024 cols x 288 k): cols 0-511 = box_W1, 512-1023 = ang_W1 (rows>=256 zero)
__global__ void prep_wcat(const float* __restrict__ box_W1, const float* __restrict__ ang_W1,
                          unsigned short* __restrict__ hi, unsigned short* __restrict__ lo) {
  int t = blockIdx.x * 256 + threadIdx.x;
  if (t >= 1024 * 288) return;
  int k = t % 288, c = t / 288;
  float v;
  if (c < 512) v = box_W1[(size_t)k * 512 + c];
  else         v = (k < 256) ? ang_W1[(size_t)k * 512 + (c - 512)] : 0.f;
  split1(v, hi[(size_t)c * 288 + k], lo[(size_t)c * 288 + k]);
}
__global__ void prep_bcat(const float* __restrict__ box_b1, const float* __restrict__ ang_b1,
                          float* __restrict__ bcat) {
  int t = blockIdx.x * 256 + threadIdx.x;
  if (t >= 1024) return;
  bcat[t] = (t < 512) ? box_b1[t] : ang_b1[t - 512];
}

// ---------------- hrel MFMA: H(N,1024 bf16) = x @ Wrel[group] ----------------
__global__ __launch_bounds__(256) void hrel_mfma(const unsigned short* __restrict__ xhi,
                                                 const unsigned short* __restrict__ xlo,
                                                 const unsigned short* __restrict__ Bh,
                                                 const unsigned short* __restrict__ Bl,
                                                 unsigned short* __restrict__ H) {
  __shared__ __align__(16) unsigned short As[2][64][136];
  __shared__ __align__(16) unsigned short Bs[2][64][136];
  const int tid = threadIdx.x;
  const int rl = blockIdx.x >> 1;
  const int col0 = (blockIdx.x & 1) * 64;
  const int row0 = blockIdx.y * 64;
  const unsigned short* Wh = Bh + ((size_t)rl * 128 + col0) * 128;
  const unsigned short* Wl = Bl + ((size_t)rl * 128 + col0) * 128;

#pragma unroll
  for (int i = 0; i < 4; ++i) {
    int c = tid + i * 256;
    int r = c >> 4;
    int k8 = (c & 15) * 8;
    int n = row0 + r;
    if (n < NN) {
      *(s8v*)&As[0][r][k8] = *(const s8v*)&xhi[(size_t)n * 128 + k8];
      *(s8v*)&As[1][r][k8] = *(const s8v*)&xlo[(size_t)n * 128 + k8];
    } else {
      s8v zz = {0, 0, 0, 0, 0, 0, 0, 0};
      *(s8v*)&As[0][r][k8] = zz;
      *(s8v*)&As[1][r][k8] = zz;
    }
    *(s8v*)&Bs[0][r][k8] = *(const s8v*)&Wh[(size_t)r * 128 + k8];
    *(s8v*)&Bs[1][r][k8] = *(const s8v*)&Wl[(size_t)r * 128 + k8];
  }
  __syncthreads();

  const int wid = tid >> 6, lane = tid & 63;
  const int mrow = (wid >> 1) * 32;
  const int ncol = (wid & 1) * 32;
  const int lr = lane & 15, lk = (lane >> 4) * 8;

  f4v acc[2][2] = {};
#pragma unroll
  for (int ks = 0; ks < 4; ++ks) {
    int kb = ks * 32 + lk;
    s8v ah0 = *(s8v*)&As[0][mrow + lr     ][kb];
    s8v ah1 = *(s8v*)&As[0][mrow + 16 + lr][kb];
    s8v al0 = *(s8v*)&As[1][mrow + lr     ][kb];
    s8v al1 = *(s8v*)&As[1][mrow + 16 + lr][kb];
    s8v bh0 = *(s8v*)&Bs[0][ncol + lr     ][kb];
    s8v bh1 = *(s8v*)&Bs[0][ncol + 16 + lr][kb];
    s8v bl0 = *(s8v*)&Bs[1][ncol + lr     ][kb];
    s8v bl1 = *(s8v*)&Bs[1][ncol + 16 + lr][kb];
    acc[0][0] = __builtin_amdgcn_mfma_f32_16x16x32_bf16(ah0, bh0, acc[0][0], 0, 0, 0);
    acc[0][1] = __builtin_amdgcn_mfma_f32_16x16x32_bf16(ah0, bh1, acc[0][1], 0, 0, 0);
    acc[1][0] = __builtin_amdgcn_mfma_f32_16x16x32_bf16(ah1, bh0, acc[1][0], 0, 0, 0);
    acc[1][1] = __builtin_amdgcn_mfma_f32_16x16x32_bf16(ah1, bh1, acc[1][1], 0, 0, 0);
    acc[0][0] = __builtin_amdgcn_mfma_f32_16x16x32_bf16(ah0, bl0, acc[0][0], 0, 0, 0);
    acc[0][1] = __builtin_amdgcn_mfma_f32_16x16x32_bf16(ah0, bl1, acc[0][1], 0, 0, 0);
    acc[1][0] = __builtin_amdgcn_mfma_f32_16x16x32_bf16(ah1, bl0, acc[1][0], 0, 0, 0);
    acc[1][1] = __builtin_amdgcn_mfma_f32_16x16x32_bf16(ah1, bl1, acc[1][1], 0, 0, 0);
    acc[0][0] = __builtin_amdgcn_mfma_f32_16x16x32_bf16(al0, bh0, acc[0][0], 0, 0, 0);
    acc[0][1] = __builtin_amdgcn_mfma_f32_16x16x32_bf16(al0, bh1, acc[0][1], 0, 0, 0);
    acc[1][0] = __builtin_amdgcn_mfma_f32_16x16x32_bf16(al1, bh0, acc[1][0], 0, 0, 0);
    acc[1][1] = __builtin_amdgcn_mfma_f32_16x16x32_bf16(al1, bh1, acc[1][1], 0, 0, 0);
  }

#pragma unroll
  for (int mf = 0; mf < 2; ++mf)
#pragma unroll
    for (int nf = 0; nf < 2; ++nf) {
      f4v v = acc[mf][nf];
      int rbase = row0 + mrow + mf * 16 + (lane >> 4) * 4;
      int cg = rl * 128 + col0 + ncol + nf * 16 + lr;
#pragma unroll
      for (int q = 0; q < 4; ++q) {
        int rr = rbase + q;
        if (rr < NN) H[(size_t)rr * 1024 + cg] = f2bf(v[q]);
      }
    }
}

// ---------------- root MFMA: y(fp32) = x @ Wroot + bias ----------------
__global__ __launch_bounds__(256) void root_mfma(const unsigned short* __restrict__ xh,
                                                 const unsigned short* __restrict__ xl,
                                                 const unsigned short* __restrict__ Bh,
                                                 const unsigned short* __restrict__ Bl,
                                                 const float* __restrict__ bias,
                                                 float* __restrict__ y) {
  __shared__ __align__(16) unsigned short As[2][64][40];
  __shared__ __align__(16) unsigned short Bs[2][128][40];
  const int tid = threadIdx.x;
  const int row0 = blockIdx.x * 64;
  const int wid = tid >> 6, lane = tid & 63;
  const int lr = lane & 15, lk = (lane >> 4) * 8;
  const int wrow = (wid >> 1) * 32, wcol = (wid & 1) * 64;
  f4v acc[2][4] = {};

  for (int k0 = 0; k0 < 128; k0 += 32) {
    __syncthreads();
    {
      int r = tid >> 2, c8 = (tid & 3) * 8, n = row0 + r;
      s8v hv, lv;
      if (n < NN) {
        hv = *(const s8v*)&xh[(size_t)n * 128 + k0 + c8];
        lv = *(const s8v*)&xl[(size_t)n * 128 + k0 + c8];
      } else {
        s8v zz = {0, 0, 0, 0, 0, 0, 0, 0};
        hv = zz; lv = zz;
      }
      *(s8v*)&As[0][r][c8] = hv;
      *(s8v*)&As[1][r][c8] = lv;
    }
#pragma unroll
    for (int i = 0; i < 2; ++i) {
      int idx = tid + i * 256, col = idx >> 2, c8 = (idx & 3) * 8;
      *(s8v*)&Bs[0][col][c8] = *(const s8v*)&Bh[(size_t)col * 128 + k0 + c8];
      *(s8v*)&Bs[1][col][c8] = *(const s8v*)&Bl[(size_t)col * 128 + k0 + c8];
    }
    __syncthreads();
#pragma unroll
    for (int mf = 0; mf < 2; ++mf) {
      s8v ah_ = *(s8v*)&As[0][wrow + mf * 16 + lr][lk];
      s8v al_ = *(s8v*)&As[1][wrow + mf * 16 + lr][lk];
#pragma unroll
      for (int nf = 0; nf < 4; ++nf) {
        s8v bh_ = *(s8v*)&Bs[0][wcol + nf * 16 + lr][lk];
        s8v bl_ = *(s8v*)&Bs[1][wcol + nf * 16 + lr][lk];
        acc[mf][nf] = __builtin_amdgcn_mfma_f32_16x16x32_bf16(ah_, bh_, acc[mf][nf], 0, 0, 0);
        acc[mf][nf] = __builtin_amdgcn_mfma_f32_16x16x32_bf16(ah_, bl_, acc[mf][nf], 0, 0, 0);
        acc[mf][nf] = __builtin_amdgcn_mfma_f32_16x16x32_bf16(al_, bh_, acc[mf][nf], 0, 0, 0);
      }
    }
  }
#pragma unroll
  for (int mf = 0; mf < 2; ++mf)
#pragma unroll
    for (int nf = 0; nf < 4; ++nf) {
      int col = wcol + nf * 16 + lr;
      float b = bias[col];
      int rbase = row0 + wrow + mf * 16 + (lane >> 4) * 4;
#pragma unroll
      for (int q = 0; q < 4; ++q) {
        int rr = rbase + q;
        if (rr < NN) y[(size_t)rr * 128 + col] = acc[mf][nf][q] + b;
      }
    }
}

// ---------------- fused MLP layer-1 MFMA: Hmlp(N,1024 bf16) = relu([x|z|attr]@Wcat + bcat) ----------------
__global__ __launch_bounds__(256) void mlpcat_mfma(const unsigned short* __restrict__ xh,
                                                   const unsigned short* __restrict__ xl,
                                                   const unsigned short* __restrict__ zh,
                                                   const unsigned short* __restrict__ zl,
                                                   const unsigned short* __restrict__ ath,
                                                   const unsigned short* __restrict__ atl,
                                                   const unsigned short* __restrict__ Wh,
                                                   const unsigned short* __restrict__ Wl,
                                                   const float* __restrict__ bcat,
                                                   unsigned short* __restrict__ H) {
  __shared__ __align__(16) unsigned short As[2][64][40];
  __shared__ __align__(16) unsigned short Bs[2][128][40];
  const int tid = threadIdx.x;
  const int row0 = blockIdx.y * 64;
  const int cb = blockIdx.x;
  const int wid = tid >> 6, lane = tid & 63;
  const int lr = lane & 15, lk = (lane >> 4) * 8;
  const int wrow = (wid >> 1) * 32, wcol = (wid & 1) * 64;
  f4v acc[2][4] = {};

  for (int step = 0; step < 9; ++step) {
    int k0 = step * 32;
    __syncthreads();
    {
      int r = tid >> 2, c8 = (tid & 3) * 8, n = row0 + r;
      s8v hv, lv;
      if (n < NN) {
        if (k0 < 128) {
          hv = *(const s8v*)&xh[(size_t)n * 128 + k0 + c8];
          lv = *(const s8v*)&xl[(size_t)n * 128 + k0 + c8];
        } else if (k0 < 256) {
          hv = *(const s8v*)&zh[(size_t)n * 128 + (k0 - 128) + c8];
          lv = *(const s8v*)&zl[(size_t)n * 128 + (k0 - 128) + c8];
        } else {
          hv = *(const s8v*)&ath[(size_t)n * 32 + (k0 - 256) + c8];
          lv = *(const s8v*)&atl[(size_t)n * 32 + (k0 - 256) + c8];
        }
      } else {
        s8v zz = {0, 0, 0, 0, 0, 0, 0, 0};
        hv = zz; lv = zz;
      }
      *(s8v*)&As[0][r][c8] = hv;
      *(s8v*)&As[1][r][c8] = lv;
    }
#pragma unroll
    for (int i = 0; i < 2; ++i) {
      int idx = tid + i * 256, col = idx >> 2, c8 = (idx & 3) * 8;
      int gc = cb * 128 + col;
      *(s8v*)&Bs[0][col][c8] = *(const s8v*)&Wh[(size_t)gc * 288 + k0 + c8];
      *(s8v*)&Bs[1][col][c8] = *(const s8v*)&Wl[(size_t)gc * 288 + k0 + c8];
    }
    __syncthreads();
#pragma unroll
    for (int mf = 0; mf < 2; ++mf) {
      s8v ah_ = *(s8v*)&As[0][wrow + mf * 16 + lr][lk];
      s8v al_ = *(s8v*)&As[1][wrow + mf * 16 + lr][lk];
#pragma unroll
      for (int nf = 0; nf < 4; ++nf) {
        s8v bh_ = *(s8v*)&Bs[0][wcol + nf * 16 + lr][lk];
        s8v bl_ = *(s8v*)&Bs[1][wcol + nf * 16 + lr][lk];
        acc[mf][nf] = __builtin_amdgcn_mfma_f32_16x16x32_bf16(ah_, bh_, acc[mf][nf], 0, 0, 0);
        acc[mf][nf] = __builtin_amdgcn_mfma_f32_16x16x32_bf16(ah_, bl_, acc[mf][nf], 0, 0, 0);
        acc[mf][nf] = __builtin_amdgcn_mfma_f32_16x16x32_bf16(al_, bh_, acc[mf][nf], 0, 0, 0);
      }
    }
  }
#pragma unroll
  for (int mf = 0; mf < 2; ++mf)
#pragma unroll
    for (int nf = 0; nf < 4; ++nf) {
      int gc = cb * 128 + wcol + nf * 16 + lr;
      float b = bcat[gc];
      int rbase = row0 + wrow + mf * 16 + (lane >> 4) * 4;
#pragma unroll
      for (int q = 0; q < 4; ++q) {
        int rr = rbase + q;
        if (rr < NN) H[(size_t)rr * 1024 + gc] = f2bf(fmaxf(acc[mf][nf][q] + b, 0.f));
      }
    }
}

// ---------------- gather: xn[o] += sum w * H[s,p]; relu + hi/lo split on last ----------------
__global__ __launch_bounds__(256) void gather_kernel(const unsigned short* __restrict__ H,
                                                     const int* __restrict__ binStart,
                                                     const int* __restrict__ offD,
                                                     const float* __restrict__ wD,
                                                     float* __restrict__ xn,
                                                     unsigned short* __restrict__ xh,
                                                     unsigned short* __restrict__ xl,
                                                     int g, int doRelu) {
  int wid = threadIdx.x >> 6, lane = threadIdx.x & 63;
  int o = blockIdx.x * 4 + wid;
  if (o >= NN) return;
  int beg = binStart[o * RREL + g * 8];
  int end = binStart[o * RREL + g * 8 + 8];
  float a0 = 0.f, a1 = 0.f, b0 = 0.f, b1 = 0.f;
  int i = beg;
  for (; i + 1 < end; i += 2) {
    int of1 = offD[i], of2 = offD[i + 1];
    float w1 = wD[i], w2 = wD[i + 1];
    unsigned int u1 = *(const unsigned int*)&H[of1 + lane * 2];
    unsigned int u2 = *(const unsigned int*)&H[of2 + lane * 2];
    a0 += w1 * bf2f(u1 & 0xffffu);
    a1 += w1 * bf2f(u1 >> 16);
    b0 += w2 * bf2f(u2 & 0xffffu);
    b1 += w2 * bf2f(u2 >> 16);
  }
  if (i < end) {
    int of1 = offD[i];
    float w1 = wD[i];
    unsigned int u1 = *(const unsigned int*)&H[of1 + lane * 2];
    a0 += w1 * bf2f(u1 & 0xffffu);
    a1 += w1 * bf2f(u1 >> 16);
  }
  a0 += b0; a1 += b1;
  float2 cur = *(float2*)&xn[(size_t)o * 128 + lane * 2];
  cur.x += a0; cur.y += a1;
  if (doRelu) {
    cur.x = fmaxf(cur.x, 0.f); cur.y = fmaxf(cur.y, 0.f);
    unsigned short h0, l0, h1, l1;
    split1(cur.x, h0, l0); split1(cur.y, h1, l1);
    *(unsigned int*)&xh[(size_t)o * 128 + lane * 2] = (unsigned int)h0 | ((unsigned int)h1 << 16);
    *(unsigned int*)&xl[(size_t)o * 128 + lane * 2] = (unsigned int)l0 | ((unsigned int)l1 << 16);
  }
  *(float2*)&xn[(size_t)o * 128 + lane * 2] = cur;
}

// ---------------- boxes head (bf16 H, cols 0..511) ----------------
__global__ __launch_bounds__(256) void box_out_kernel(const unsigned short* __restrict__ H,
                                                      const float* __restrict__ W2,
                                                      const float* __restrict__ b2,
                                                      float* __restrict__ out) {
  __shared__ float w2s[512 * 6];
  for (int i = threadIdx.x; i < 512 * 6; i += 256) w2s[i] = W2[i];
  __syncthreads();
  int wid = threadIdx.x >> 6, lane = threadIdx.x & 63;
  int n = blockIdx.x * 4 + wid;
  if (n >= NN) return;
  float a[6] = {0.f, 0.f, 0.f, 0.f, 0.f, 0.f};
#pragma unroll
  for (int j = 0; j < 4; ++j) {
    int col = j * 128 + lane * 2;
    unsigned int u = *(const unsigned int*)&H[(size_t)n * 1024 + col];
    float v0 = bf2f(u & 0xffffu), v1 = bf2f(u >> 16);
#pragma unroll
    for (int c = 0; c < 6; ++c) a[c] += v0 * w2s[col * 6 + c] + v1 * w2s[(col + 1) * 6 + c];
  }
#pragma unroll
  for (int m = 32; m > 0; m >>= 1) {
#pragma unroll
    for (int c = 0; c < 6; ++c) a[c] += __shfl_xor(a[c], m, 64);
  }
  if (lane == 0) {
#pragma unroll
    for (int c = 0; c < 6; ++c) out[(size_t)n * 6 + c] = a[c] + b2[c];
  }
}

// ---------------- angles head (bf16 H, cols 512..1023) ----------------
__global__ __launch_bounds__(256) void ang_out_kernel(const unsigned short* __restrict__ H,
                                                      const float* __restrict__ W2,
                                                      const float* __restrict__ b2,
                                                      float* __restrict__ out) {
  __shared__ float w2s[512][25];
  __shared__ float b2s[24];
  for (int i = threadIdx.x; i < 512 * 24; i += 256) {
    int h = i / 24, c = i % 24;
    w2s[h][c] = W2[i];
  }
  if (threadIdx.x < 24) b2s[threadIdx.x] = b2[threadIdx.x];
  __syncthreads();
  int wid = threadIdx.x >> 6, lane = threadIdx.x & 63;
  int n = blockIdx.x * 4 + wid;
  if (n >= NN) return;
  float a[24];
#pragma unroll
  for (int c = 0; c < 24; ++c) a[c] = 0.f;
#pragma unroll
  for (int j = 0; j < 4; ++j) {
    int col = j * 128 + lane * 2;
    unsigned int u = *(const unsigned int*)&H[(size_t)n * 1024 + 512 + col];
    float v0 = bf2f(u & 0xffffu), v1 = bf2f(u >> 16);
#pragma unroll
    for (int c = 0; c < 24; ++c) a[c] += v0 * w2s[col][c] + v1 * w2s[col + 1][c];
  }
#pragma unroll
  for (int m = 32; m > 0; m >>= 1) {
#pragma unroll
    for (int c = 0; c < 24; ++c) a[c] += __shfl_xor(a[c], m, 64);
  }
#pragma unroll
  for (int c = 0; c < 24; ++c) a[c] += b2s[c];
  float mx = a[0];
#pragma unroll
  for (int c = 1; c < 24; ++c) mx = fmaxf(mx, a[c]);
  float ssum = 0.f;
#pragma unroll
  for (int c = 0; c < 24; ++c) ssum += expf(a[c] - mx);
  float lse = mx + logf(ssum);
  if (lane == 0) {
#pragma unroll
    for (int c = 0; c < 24; ++c) out[(size_t)n * 24 + c] = a[c] - lse;
  }
}

// ------------------------------------------------------------------------
extern "C" void kernel_launch(void* const* d_in, const int* in_sizes, int n_in,
                              void* d_out, int out_size, void* d_ws, size_t ws_size,
                              hipStream_t stream) {
  const float* z        = (const float*)d_in[0];
  const int*   objs     = (const int*)d_in[1];
  const int*   triples  = (const int*)d_in[2];
  const int*   attrs    = (const int*)d_in[3];
  const float* obj_emb  = (const float*)d_in[4];
  const float* attr_emb = (const float*)d_in[5];
  const float* Wrel     = (const float*)d_in[6];
  const float* Wroot    = (const float*)d_in[7];
  const float* bconv    = (const float*)d_in[8];
  const float* box_W1   = (const float*)d_in[9];
  const float* box_b1   = (const float*)d_in[10];
  const float* box_W2   = (const float*)d_in[11];
  const float* box_b2   = (const float*)d_in[12];
  const float* ang_W1   = (const float*)d_in[13];
  const float* ang_b1   = (const float*)d_in[14];
  const float* ang_W2   = (const float*)d_in[15];
  const float* ang_b2   = (const float*)d_in[16];
  float* out = (float*)d_out;

  char* base = (char*)d_ws;
  size_t cur = 0;
  auto alloc = [&](size_t bytes) -> char* {
    char* p = base + cur;
    cur += (bytes + 255) & ~(size_t)255;
    return p;
  };
  float* x0            = (float*)alloc((size_t)NN * 128 * 4);
  float* x1            = (float*)alloc((size_t)NN * 128 * 4);
  unsigned short* Hb   = (unsigned short*)alloc((size_t)NN * 1024 * 2);
  unsigned short* xhi  = (unsigned short*)alloc((size_t)NN * 128 * 2);
  unsigned short* xlo  = (unsigned short*)alloc((size_t)NN * 128 * 2);
  unsigned short* zhi  = (unsigned short*)alloc((size_t)NN * 128 * 2);
  unsigned short* zlo  = (unsigned short*)alloc((size_t)NN * 128 * 2);
  unsigned short* athi = (unsigned short*)alloc((size_t)NN * 32 * 2);
  unsigned short* atlo = (unsigned short*)alloc((size_t)NN * 32 * 2);
  unsigned short* WThi = (unsigned short*)alloc((size_t)LLAY * RREL * 128 * 128 * 2);
  unsigned short* WTlo = (unsigned short*)alloc((size_t)LLAY * RREL * 128 * 128 * 2);
  unsigned short* WrtH = (unsigned short*)alloc((size_t)LLAY * 128 * 128 * 2);
  unsigned short* WrtL = (unsigned short*)alloc((size_t)LLAY * 128 * 128 * 2);
  unsigned short* WcH  = (unsigned short*)alloc((size_t)1024 * 288 * 2);
  unsigned short* WcL  = (unsigned short*)alloc((size_t)1024 * 288 * 2);
  float* bcat          = (float*)alloc(1024 * 4);
  int*   cnt      = (int*)alloc((size_t)NBINS * 4);
  int*   binStart = (int*)alloc((size_t)(NBINS + 1) * 4);
  int*   cursor   = (int*)alloc((size_t)NBINS * 4);
  int*   partial  = (int*)alloc(4096);
  int*   offD     = (int*)alloc((size_t)EE * 4);
  float* wD       = (float*)alloc((size_t)EE * 4);

  hipMemsetAsync(cnt, 0, (size_t)NBINS * 4, stream);
  hipMemsetAsync(cursor, 0, (size_t)NBINS * 4, stream);

  build_x0_kernel<<<(NN * 32 + 255) / 256, 256, 0, stream>>>(objs, attrs, obj_emb, attr_emb,
                                                             x0, xhi, xlo);
  prep_zattr<<<(NN * 40 + 255) / 256, 256, 0, stream>>>(z, attrs, attr_emb, zhi, zlo, athi, atlo);
  count_kernel<<<(EE + 255) / 256, 256, 0, stream>>>(triples, cnt);
  const int nPart = (NBINS + 1023) / 1024;
  scanA<<<nPart, 1024, 0, stream>>>(cnt, binStart, partial);
  scanB<<<1, 1024, 0, stream>>>(partial, binStart, nPart);
  scanC<<<nPart, 1024, 0, stream>>>(binStart, partial);
  place_kernel<<<(EE + 255) / 256, 256, 0, stream>>>(triples, cnt, binStart, cursor, offD, wD);
  prep_wrel<<<(LLAY * RREL * 128 * 128 + 255) / 256, 256, 0, stream>>>(Wrel, WThi, WTlo);
  prep_wroot<<<(LLAY * 128 * 128 + 255) / 256, 256, 0, stream>>>(Wroot, WrtH, WrtL);
  prep_wcat<<<(1024 * 288 + 255) / 256, 256, 0, stream>>>(box_W1, ang_W1, WcH, WcL);
  prep_bcat<<<4, 256, 0, stream>>>(box_b1, ang_b1, bcat);

  float* xc = x0;
  float* xn = x1;
  const int rowBlocks = (NN + 63) / 64;   // 782
  for (int j = 0; j < LLAY; ++j) {
    root_mfma<<<rowBlocks, 256, 0, stream>>>(xhi, xlo, WrtH + (size_t)j * 128 * 128,
                                             WrtL + (size_t)j * 128 * 128,
                                             bconv + (size_t)j * 128, xn);
    for (int g = 0; g < 2; ++g) {
      const unsigned short* Bh = WThi + ((size_t)j * RREL + g * 8) * 128 * 128;
      const unsigned short* Bl = WTlo + ((size_t)j * RREL + g * 8) * 128 * 128;
      hrel_mfma<<<dim3(16, rowBlocks), 256, 0, stream>>>(xhi, xlo, Bh, Bl, Hb);
      gather_kernel<<<(NN + 3) / 4, 256, 0, stream>>>(Hb, binStart, offD, wD, xn,
                                                      xhi, xlo, g, (g == 1) ? 1 : 0);
    }
    float* tmp = xc; xc = xn; xn = tmp;
  }

  mlpcat_mfma<<<dim3(8, rowBlocks), 256, 0, stream>>>(xhi, xlo, zhi, zlo, athi, atlo,
                                                      WcH, WcL, bcat, Hb);
  box_out_kernel<<<(NN + 3) / 4, 256, 0, stream>>>(Hb, box_W2, box_b2, out);
  ang_out_kernel<<<(NN + 3) / 4, 256, 0, stream>>>(Hb, ang_W2, ang_b2, out + (size_t)NN * 6);
}

// Round 4
// 1416.702 us; speedup vs baseline: 7.7504x; 1.2988x over previous
//
#include <hip/hip_runtime.h>
#include <hip/hip_bf16.h>
#include <math.h>

#define NN   50000
#define EE   800000
#define RREL 16
#define LLAY 5
#define NBINS (NN * RREL)

typedef __attribute__((ext_vector_type(8))) short s8v;
typedef __attribute__((ext_vector_type(4))) float f4v;

__device__ __forceinline__ unsigned short f2bf(float f) {
  __hip_bfloat16 h = __float2bfloat16(f);
  return __builtin_bit_cast(unsigned short, h);
}
__device__ __forceinline__ float bf2f(unsigned int u) {
  return __builtin_bit_cast(float, u << 16);
}
__device__ __forceinline__ void split1(float v, unsigned short& h, unsigned short& l) {
  __hip_bfloat16 hb = __float2bfloat16(v);
  float hf = __bfloat162float(hb);
  h = __builtin_bit_cast(unsigned short, hb);
  __hip_bfloat16 lb = __float2bfloat16(v - hf);
  l = __builtin_bit_cast(unsigned short, lb);
}

// ---------------- build x0 (fp32) + hi/lo split ----------------
__global__ void build_x0_kernel(const int* __restrict__ objs, const int* __restrict__ attrs,
                                const float* __restrict__ obj_emb, const float* __restrict__ attr_emb,
                                float* __restrict__ x0, unsigned short* __restrict__ xh,
                                unsigned short* __restrict__ xl) {
  int t = blockIdx.x * blockDim.x + threadIdx.x;
  if (t >= NN * 32) return;
  int n = t >> 5, q = t & 31;
  float4 v;
  if (q < 24) v = *(const float4*)&obj_emb[(size_t)objs[n] * 96 + q * 4];
  else        v = *(const float4*)&attr_emb[(size_t)attrs[n] * 32 + (q - 24) * 4];
  *(float4*)&x0[(size_t)n * 128 + q * 4] = v;
  ushort4 h, l;
  split1(v.x, h.x, l.x); split1(v.y, h.y, l.y);
  split1(v.z, h.z, l.z); split1(v.w, h.w, l.w);
  *(ushort4*)&xh[(size_t)n * 128 + q * 4] = h;
  *(ushort4*)&xl[(size_t)n * 128 + q * 4] = l;
}

// ---------------- split z (N,128) and attr_emb[attrs] (N,32) ----------------
__global__ void prep_zattr(const float* __restrict__ z, const int* __restrict__ attrs,
                           const float* __restrict__ attr_emb,
                           unsigned short* __restrict__ zh, unsigned short* __restrict__ zl,
                           unsigned short* __restrict__ ah, unsigned short* __restrict__ al) {
  int t = blockIdx.x * blockDim.x + threadIdx.x;
  if (t >= NN * 40) return;
  int n = t / 40, q = t % 40;
  float4 v;
  ushort4 h, l;
  if (q < 32) {
    v = *(const float4*)&z[(size_t)n * 128 + q * 4];
    split1(v.x, h.x, l.x); split1(v.y, h.y, l.y);
    split1(v.z, h.z, l.z); split1(v.w, h.w, l.w);
    *(ushort4*)&zh[(size_t)n * 128 + q * 4] = h;
    *(ushort4*)&zl[(size_t)n * 128 + q * 4] = l;
  } else {
    int qq = q - 32;
    v = *(const float4*)&attr_emb[(size_t)attrs[n] * 32 + qq * 4];
    split1(v.x, h.x, l.x); split1(v.y, h.y, l.y);
    split1(v.z, h.z, l.z); split1(v.w, h.w, l.w);
    *(ushort4*)&ah[(size_t)n * 32 + qq * 4] = h;
    *(ushort4*)&al[(size_t)n * 32 + qq * 4] = l;
  }
}

// ---------------- count / scan / place ----------------
__global__ void count_kernel(const int* __restrict__ triples, int* __restrict__ cnt) {
  int e = blockIdx.x * 256 + threadIdx.x;
  if (e >= EE) return;
  int p = triples[e * 3 + 1], o = triples[e * 3 + 2];
  atomicAdd(&cnt[o * RREL + p], 1);
}
__global__ void scanA(const int* __restrict__ cnt, int* __restrict__ binStart,
                      int* __restrict__ partial) {
  __shared__ int buf[1024];
  int g = blockIdx.x * 1024 + threadIdx.x;
  int v = (g < NBINS) ? cnt[g] : 0;
  buf[threadIdx.x] = v;
  __syncthreads();
  for (int d = 1; d < 1024; d <<= 1) {
    int t = (threadIdx.x >= d) ? buf[threadIdx.x - d] : 0;
    __syncthreads();
    buf[threadIdx.x] += t;
    __syncthreads();
  }
  if (g < NBINS) binStart[g] = buf[threadIdx.x] - v;
  if (threadIdx.x == 1023) partial[blockIdx.x] = buf[1023];
}
__global__ void scanB(int* __restrict__ partial, int* __restrict__ binStart, int nPart) {
  __shared__ int buf[1024];
  int v = (threadIdx.x < nPart) ? partial[threadIdx.x] : 0;
  buf[threadIdx.x] = v;
  __syncthreads();
  for (int d = 1; d < 1024; d <<= 1) {
    int t = (threadIdx.x >= d) ? buf[threadIdx.x - d] : 0;
    __syncthreads();
    buf[threadIdx.x] += t;
    __syncthreads();
  }
  if (threadIdx.x < nPart) partial[threadIdx.x] = buf[threadIdx.x] - v;
  if (threadIdx.x == 1023) binStart[NBINS] = buf[1023];
}
__global__ void scanC(int* __restrict__ binStart, const int* __restrict__ partial) {
  int g = blockIdx.x * 1024 + threadIdx.x;
  if (g < NBINS) binStart[g] += partial[blockIdx.x];
}
__global__ void place_kernel(const int* __restrict__ triples, const int* __restrict__ cnt,
                             const int* __restrict__ binStart, int* __restrict__ cursor,
                             int* __restrict__ offD, float* __restrict__ wD) {
  int e = blockIdx.x * 256 + threadIdx.x;
  if (e >= EE) return;
  int s = triples[e * 3 + 0], p = triples[e * 3 + 1], o = triples[e * 3 + 2];
  int bin = o * RREL + p;
  int pos = binStart[bin] + atomicAdd(&cursor[bin], 1);
  offD[pos] = s * 1024 + (p & 7) * 128;
  wD[pos] = 1.0f / (float)cnt[bin];
}

// ---------------- weight preps (transpose + hi/lo split) ----------------
__global__ void prep_wrel(const float* __restrict__ Wrel, unsigned short* __restrict__ WThi,
                          unsigned short* __restrict__ WTlo) {
  int t = blockIdx.x * 256 + threadIdx.x;
  if (t >= LLAY * RREL * 128 * 128) return;
  int f = t & 127, k = (t >> 7) & 127, lr = t >> 14;
  float v = Wrel[((size_t)lr * 128 + k) * 128 + f];
  size_t di = ((size_t)lr * 128 + f) * 128 + k;
  split1(v, WThi[di], WTlo[di]);
}
__global__ void prep_wroot(const float* __restrict__ Wroot, unsigned short* __restrict__ hi,
                           unsigned short* __restrict__ lo) {
  int t = blockIdx.x * 256 + threadIdx.x;
  if (t >= LLAY * 128 * 128) return;
  int f = t & 127, k = (t >> 7) & 127, l = t >> 14;
  float v = Wroot[((size_t)l * 128 + k) * 128 + f];
  size_t di = ((size_t)l * 128 + f) * 128 + k;
  split1(v, hi[di], lo[di]);
}
// Wcat (1024 cols x 288 k): cols 0-511 = box_W1, 512-1023 = ang_W1 (rows>=256 zero)
__global__ void prep_wcat(const float* __restrict__ box_W1, const float* __restrict__ ang_W1,
                          unsigned short* __restrict__ hi, unsigned short* __restrict__ lo) {
  int t = blockIdx.x * 256 + threadIdx.x;
  if (t >= 1024 * 288) return;
  int k = t % 288, c = t / 288;
  float v;
  if (c < 512) v = box_W1[(size_t)k * 512 + c];
  else         v = (k < 256) ? ang_W1[(size_t)k * 512 + (c - 512)] : 0.f;
  split1(v, hi[(size_t)c * 288 + k], lo[(size_t)c * 288 + k]);
}
__global__ void prep_bcat(const float* __restrict__ box_b1, const float* __restrict__ ang_b1,
                          float* __restrict__ bcat) {
  int t = blockIdx.x * 256 + threadIdx.x;
  if (t >= 1024) return;
  bcat[t] = (t < 512) ? box_b1[t] : ang_b1[t - 512];
}
// W2cat (32 cols x 1024 k): cols 0-5 box_W2 (k<512), cols 6-29 ang_W2 (k>=512), else 0
__global__ void prep_w2cat(const float* __restrict__ box_W2, const float* __restrict__ ang_W2,
                           unsigned short* __restrict__ hi, unsigned short* __restrict__ lo) {
  int t = blockIdx.x * 256 + threadIdx.x;
  if (t >= 32 * 1024) return;
  int k = t & 1023, c = t >> 10;
  float v = 0.f;
  if (c < 6)       { if (k < 512)  v = box_W2[(size_t)k * 6 + c]; }
  else if (c < 30) { if (k >= 512) v = ang_W2[(size_t)(k - 512) * 24 + (c - 6)]; }
  split1(v, hi[(size_t)c * 1024 + k], lo[(size_t)c * 1024 + k]);
}

// ---------------- hrel MFMA: H(N,1024 bf16) = x @ Wrel[group], 128x128 tiles ----------------
// grid: (8, 391); blockIdx.x = relation-in-group (128 cols); blockIdx.y = 128-row tile
__global__ __launch_bounds__(256) void hrel_mfma(const unsigned short* __restrict__ xhi,
                                                 const unsigned short* __restrict__ xlo,
                                                 const unsigned short* __restrict__ Bh,
                                                 const unsigned short* __restrict__ Bl,
                                                 unsigned short* __restrict__ H) {
  __shared__ __align__(16) unsigned short As[2][128][40];
  __shared__ __align__(16) unsigned short Bs[2][128][40];
  const int tid = threadIdx.x;
  const int rl = blockIdx.x;
  const int row0 = blockIdx.y * 128;
  const int wid = tid >> 6, lane = tid & 63;
  const int wrow = (wid >> 1) * 64, wcol = (wid & 1) * 64;
  const int lr = lane & 15, lk = (lane >> 4) * 8;
  const unsigned short* Wbase[2] = { Bh + (size_t)rl * 128 * 128, Bl + (size_t)rl * 128 * 128 };
  f4v acc[4][4] = {};

  for (int k0 = 0; k0 < 128; k0 += 32) {
    __syncthreads();
#pragma unroll
    for (int i = 0; i < 4; ++i) {
      const int hl = i >> 1;
      const int idx = tid + (i & 1) * 256;   // 0..511
      const int r = idx >> 2;                // 0..127
      const int c8 = (idx & 3) * 8;
      int n = row0 + r;
      s8v v;
      if (n < NN) {
        const unsigned short* xp = hl ? xlo : xhi;
        v = *(const s8v*)&xp[(size_t)n * 128 + k0 + c8];
      } else {
        s8v zz = {0, 0, 0, 0, 0, 0, 0, 0};
        v = zz;
      }
      *(s8v*)&As[hl][r][c8] = v;
      *(s8v*)&Bs[hl][r][c8] = *(const s8v*)&Wbase[hl][(size_t)r * 128 + k0 + c8];
    }
    __syncthreads();

    s8v ah[4], al[4];
#pragma unroll
    for (int mf = 0; mf < 4; ++mf) {
      ah[mf] = *(s8v*)&As[0][wrow + mf * 16 + lr][lk];
      al[mf] = *(s8v*)&As[1][wrow + mf * 16 + lr][lk];
    }
#pragma unroll
    for (int nf = 0; nf < 4; ++nf) {
      s8v bh_ = *(s8v*)&Bs[0][wcol + nf * 16 + lr][lk];
      s8v bl_ = *(s8v*)&Bs[1][wcol + nf * 16 + lr][lk];
#pragma unroll
      for (int mf = 0; mf < 4; ++mf) {
        acc[mf][nf] = __builtin_amdgcn_mfma_f32_16x16x32_bf16(ah[mf], bh_, acc[mf][nf], 0, 0, 0);
        acc[mf][nf] = __builtin_amdgcn_mfma_f32_16x16x32_bf16(ah[mf], bl_, acc[mf][nf], 0, 0, 0);
        acc[mf][nf] = __builtin_amdgcn_mfma_f32_16x16x32_bf16(al[mf], bh_, acc[mf][nf], 0, 0, 0);
      }
    }
  }

#pragma unroll
  for (int mf = 0; mf < 4; ++mf)
#pragma unroll
    for (int nf = 0; nf < 4; ++nf) {
      f4v v = acc[mf][nf];
      int rbase = row0 + wrow + mf * 16 + (lane >> 4) * 4;
      int cg = rl * 128 + wcol + nf * 16 + lr;
#pragma unroll
      for (int q = 0; q < 4; ++q) {
        int rr = rbase + q;
        if (rr < NN) H[(size_t)rr * 1024 + cg] = f2bf(v[q]);
      }
    }
}

// ---------------- root MFMA: y(fp32) = x @ Wroot + bias ----------------
__global__ __launch_bounds__(256) void root_mfma(const unsigned short* __restrict__ xh,
                                                 const unsigned short* __restrict__ xl,
                                                 const unsigned short* __restrict__ Bh,
                                                 const unsigned short* __restrict__ Bl,
                                                 const float* __restrict__ bias,
                                                 float* __restrict__ y) {
  __shared__ __align__(16) unsigned short As[2][64][40];
  __shared__ __align__(16) unsigned short Bs[2][128][40];
  const int tid = threadIdx.x;
  const int row0 = blockIdx.x * 64;
  const int wid = tid >> 6, lane = tid & 63;
  const int lr = lane & 15, lk = (lane >> 4) * 8;
  const int wrow = (wid >> 1) * 32, wcol = (wid & 1) * 64;
  f4v acc[2][4] = {};

  for (int k0 = 0; k0 < 128; k0 += 32) {
    __syncthreads();
    {
      int r = tid >> 2, c8 = (tid & 3) * 8, n = row0 + r;
      s8v hv, lv;
      if (n < NN) {
        hv = *(const s8v*)&xh[(size_t)n * 128 + k0 + c8];
        lv = *(const s8v*)&xl[(size_t)n * 128 + k0 + c8];
      } else {
        s8v zz = {0, 0, 0, 0, 0, 0, 0, 0};
        hv = zz; lv = zz;
      }
      *(s8v*)&As[0][r][c8] = hv;
      *(s8v*)&As[1][r][c8] = lv;
    }
#pragma unroll
    for (int i = 0; i < 2; ++i) {
      int idx = tid + i * 256, col = idx >> 2, c8 = (idx & 3) * 8;
      *(s8v*)&Bs[0][col][c8] = *(const s8v*)&Bh[(size_t)col * 128 + k0 + c8];
      *(s8v*)&Bs[1][col][c8] = *(const s8v*)&Bl[(size_t)col * 128 + k0 + c8];
    }
    __syncthreads();
#pragma unroll
    for (int mf = 0; mf < 2; ++mf) {
      s8v ah_ = *(s8v*)&As[0][wrow + mf * 16 + lr][lk];
      s8v al_ = *(s8v*)&As[1][wrow + mf * 16 + lr][lk];
#pragma unroll
      for (int nf = 0; nf < 4; ++nf) {
        s8v bh_ = *(s8v*)&Bs[0][wcol + nf * 16 + lr][lk];
        s8v bl_ = *(s8v*)&Bs[1][wcol + nf * 16 + lr][lk];
        acc[mf][nf] = __builtin_amdgcn_mfma_f32_16x16x32_bf16(ah_, bh_, acc[mf][nf], 0, 0, 0);
        acc[mf][nf] = __builtin_amdgcn_mfma_f32_16x16x32_bf16(ah_, bl_, acc[mf][nf], 0, 0, 0);
        acc[mf][nf] = __builtin_amdgcn_mfma_f32_16x16x32_bf16(al_, bh_, acc[mf][nf], 0, 0, 0);
      }
    }
  }
#pragma unroll
  for (int mf = 0; mf < 2; ++mf)
#pragma unroll
    for (int nf = 0; nf < 4; ++nf) {
      int col = wcol + nf * 16 + lr;
      float b = bias[col];
      int rbase = row0 + wrow + mf * 16 + (lane >> 4) * 4;
#pragma unroll
      for (int q = 0; q < 4; ++q) {
        int rr = rbase + q;
        if (rr < NN) y[(size_t)rr * 128 + col] = acc[mf][nf][q] + b;
      }
    }
}

// ---------------- fused MLP layer-1 MFMA: Hmlp(N,1024 bf16) = relu([x|z|attr]@Wcat + bcat) ----------------
__global__ __launch_bounds__(256) void mlpcat_mfma(const unsigned short* __restrict__ xh,
                                                   const unsigned short* __restrict__ xl,
                                                   const unsigned short* __restrict__ zh,
                                                   const unsigned short* __restrict__ zl,
                                                   const unsigned short* __restrict__ ath,
                                                   const unsigned short* __restrict__ atl,
                                                   const unsigned short* __restrict__ Wh,
                                                   const unsigned short* __restrict__ Wl,
                                                   const float* __restrict__ bcat,
                                                   unsigned short* __restrict__ H) {
  __shared__ __align__(16) unsigned short As[2][64][40];
  __shared__ __align__(16) unsigned short Bs[2][128][40];
  const int tid = threadIdx.x;
  const int row0 = blockIdx.y * 64;
  const int cb = blockIdx.x;
  const int wid = tid >> 6, lane = tid & 63;
  const int lr = lane & 15, lk = (lane >> 4) * 8;
  const int wrow = (wid >> 1) * 32, wcol = (wid & 1) * 64;
  f4v acc[2][4] = {};

  for (int step = 0; step < 9; ++step) {
    int k0 = step * 32;
    __syncthreads();
    {
      int r = tid >> 2, c8 = (tid & 3) * 8, n = row0 + r;
      s8v hv, lv;
      if (n < NN) {
        if (k0 < 128) {
          hv = *(const s8v*)&xh[(size_t)n * 128 + k0 + c8];
          lv = *(const s8v*)&xl[(size_t)n * 128 + k0 + c8];
        } else if (k0 < 256) {
          hv = *(const s8v*)&zh[(size_t)n * 128 + (k0 - 128) + c8];
          lv = *(const s8v*)&zl[(size_t)n * 128 + (k0 - 128) + c8];
        } else {
          hv = *(const s8v*)&ath[(size_t)n * 32 + (k0 - 256) + c8];
          lv = *(const s8v*)&atl[(size_t)n * 32 + (k0 - 256) + c8];
        }
      } else {
        s8v zz = {0, 0, 0, 0, 0, 0, 0, 0};
        hv = zz; lv = zz;
      }
      *(s8v*)&As[0][r][c8] = hv;
      *(s8v*)&As[1][r][c8] = lv;
    }
#pragma unroll
    for (int i = 0; i < 2; ++i) {
      int idx = tid + i * 256, col = idx >> 2, c8 = (idx & 3) * 8;
      int gc = cb * 128 + col;
      *(s8v*)&Bs[0][col][c8] = *(const s8v*)&Wh[(size_t)gc * 288 + k0 + c8];
      *(s8v*)&Bs[1][col][c8] = *(const s8v*)&Wl[(size_t)gc * 288 + k0 + c8];
    }
    __syncthreads();
#pragma unroll
    for (int mf = 0; mf < 2; ++mf) {
      s8v ah_ = *(s8v*)&As[0][wrow + mf * 16 + lr][lk];
      s8v al_ = *(s8v*)&As[1][wrow + mf * 16 + lr][lk];
#pragma unroll
      for (int nf = 0; nf < 4; ++nf) {
        s8v bh_ = *(s8v*)&Bs[0][wcol + nf * 16 + lr][lk];
        s8v bl_ = *(s8v*)&Bs[1][wcol + nf * 16 + lr][lk];
        acc[mf][nf] = __builtin_amdgcn_mfma_f32_16x16x32_bf16(ah_, bh_, acc[mf][nf], 0, 0, 0);
        acc[mf][nf] = __builtin_amdgcn_mfma_f32_16x16x32_bf16(ah_, bl_, acc[mf][nf], 0, 0, 0);
        acc[mf][nf] = __builtin_amdgcn_mfma_f32_16x16x32_bf16(al_, bh_, acc[mf][nf], 0, 0, 0);
      }
    }
  }
#pragma unroll
  for (int mf = 0; mf < 2; ++mf)
#pragma unroll
    for (int nf = 0; nf < 4; ++nf) {
      int gc = cb * 128 + wcol + nf * 16 + lr;
      float b = bcat[gc];
      int rbase = row0 + wrow + mf * 16 + (lane >> 4) * 4;
#pragma unroll
      for (int q = 0; q < 4; ++q) {
        int rr = rbase + q;
        if (rr < NN) H[(size_t)rr * 1024 + gc] = f2bf(fmaxf(acc[mf][nf][q] + b, 0.f));
      }
    }
}

// ---------------- head MFMA: logits(N,32 f32) = H(N,1024 bf16) @ W2cat(1024x32) ----------------
// grid: 196; block 256 = 4 waves; block covers 256 rows x 32 cols
__global__ __launch_bounds__(256) void head_mfma(const unsigned short* __restrict__ H,
                                                 const unsigned short* __restrict__ Wh,
                                                 const unsigned short* __restrict__ Wl,
                                                 float* __restrict__ logits) {
  __shared__ __align__(16) unsigned short As[256][40];
  __shared__ __align__(16) unsigned short Bs[2][32][40];
  const int tid = threadIdx.x;
  const int row0 = blockIdx.x * 256;
  const int wid = tid >> 6, lane = tid & 63;
  const int wrow = wid * 64;
  const int lr = lane & 15, lk = (lane >> 4) * 8;
  f4v acc[4][2] = {};

  for (int k0 = 0; k0 < 1024; k0 += 32) {
    __syncthreads();
#pragma unroll
    for (int i = 0; i < 4; ++i) {
      int idx = tid + i * 256;      // 0..1023
      int r = idx >> 2, c8 = (idx & 3) * 8;
      int n = row0 + r;
      s8v v;
      if (n < NN) v = *(const s8v*)&H[(size_t)n * 1024 + k0 + c8];
      else { s8v zz = {0, 0, 0, 0, 0, 0, 0, 0}; v = zz; }
      *(s8v*)&As[r][c8] = v;
    }
    {
      int hl = tid >> 7, rem = tid & 127;
      int col = rem >> 2, c8 = (rem & 3) * 8;
      const unsigned short* Wp = hl ? Wl : Wh;
      *(s8v*)&Bs[hl][col][c8] = *(const s8v*)&Wp[(size_t)col * 1024 + k0 + c8];
    }
    __syncthreads();
#pragma unroll
    for (int nf = 0; nf < 2; ++nf) {
      s8v bh_ = *(s8v*)&Bs[0][nf * 16 + lr][lk];
      s8v bl_ = *(s8v*)&Bs[1][nf * 16 + lr][lk];
#pragma unroll
      for (int mf = 0; mf < 4; ++mf) {
        s8v a_ = *(s8v*)&As[wrow + mf * 16 + lr][lk];
        acc[mf][nf] = __builtin_amdgcn_mfma_f32_16x16x32_bf16(a_, bh_, acc[mf][nf], 0, 0, 0);
        acc[mf][nf] = __builtin_amdgcn_mfma_f32_16x16x32_bf16(a_, bl_, acc[mf][nf], 0, 0, 0);
      }
    }
  }
#pragma unroll
  for (int mf = 0; mf < 4; ++mf)
#pragma unroll
    for (int nf = 0; nf < 2; ++nf) {
      int col = nf * 16 + lr;
      int rbase = row0 + wrow + mf * 16 + (lane >> 4) * 4;
#pragma unroll
      for (int q = 0; q < 4; ++q) {
        int rr = rbase + q;
        if (rr < NN) logits[(size_t)rr * 32 + col] = acc[mf][nf][q];
      }
    }
}

// ---------------- head epilogue: biases + box copy + ang log_softmax ----------------
__global__ void head_post(const float* __restrict__ logits, const float* __restrict__ box_b2,
                          const float* __restrict__ ang_b2, float* __restrict__ out) {
  int n = blockIdx.x * 256 + threadIdx.x;
  if (n >= NN) return;
  float l[32];
#pragma unroll
  for (int i = 0; i < 8; ++i)
    *(float4*)&l[i * 4] = *(const float4*)&logits[(size_t)n * 32 + i * 4];
  float* ob = out + (size_t)n * 6;
#pragma unroll
  for (int c = 0; c < 6; ++c) ob[c] = l[c] + box_b2[c];
  float a[24];
  float mx = -1e30f;
#pragma unroll
  for (int c = 0; c < 24; ++c) { a[c] = l[6 + c] + ang_b2[c]; mx = fmaxf(mx, a[c]); }
  float ssum = 0.f;
#pragma unroll
  for (int c = 0; c < 24; ++c) ssum += expf(a[c] - mx);
  float lse = mx + logf(ssum);
  float* oa = out + (size_t)NN * 6 + (size_t)n * 24;
#pragma unroll
  for (int c = 0; c < 24; ++c) oa[c] = a[c] - lse;
}

// ---------------- gather: xn[o] += sum w * H[s,p]; relu + hi/lo split on last ----------------
__global__ __launch_bounds__(256) void gather_kernel(const unsigned short* __restrict__ H,
                                                     const int* __restrict__ binStart,
                                                     const int* __restrict__ offD,
                                                     const float* __restrict__ wD,
                                                     float* __restrict__ xn,
                                                     unsigned short* __restrict__ xh,
                                                     unsigned short* __restrict__ xl,
                                                     int g, int doRelu) {
  int wid = threadIdx.x >> 6, lane = threadIdx.x & 63;
  int o = blockIdx.x * 4 + wid;
  if (o >= NN) return;
  int beg = binStart[o * RREL + g * 8];
  int end = binStart[o * RREL + g * 8 + 8];
  float a0 = 0.f, a1 = 0.f, b0 = 0.f, b1 = 0.f;
  int i = beg;
  for (; i + 1 < end; i += 2) {
    int of1 = offD[i], of2 = offD[i + 1];
    float w1 = wD[i], w2 = wD[i + 1];
    unsigned int u1 = *(const unsigned int*)&H[of1 + lane * 2];
    unsigned int u2 = *(const unsigned int*)&H[of2 + lane * 2];
    a0 += w1 * bf2f(u1 & 0xffffu);
    a1 += w1 * bf2f(u1 >> 16);
    b0 += w2 * bf2f(u2 & 0xffffu);
    b1 += w2 * bf2f(u2 >> 16);
  }
  if (i < end) {
    int of1 = offD[i];
    float w1 = wD[i];
    unsigned int u1 = *(const unsigned int*)&H[of1 + lane * 2];
    a0 += w1 * bf2f(u1 & 0xffffu);
    a1 += w1 * bf2f(u1 >> 16);
  }
  a0 += b0; a1 += b1;
  float2 cur = *(float2*)&xn[(size_t)o * 128 + lane * 2];
  cur.x += a0; cur.y += a1;
  if (doRelu) {
    cur.x = fmaxf(cur.x, 0.f); cur.y = fmaxf(cur.y, 0.f);
    unsigned short h0, l0, h1, l1;
    split1(cur.x, h0, l0); split1(cur.y, h1, l1);
    *(unsigned int*)&xh[(size_t)o * 128 + lane * 2] = (unsigned int)h0 | ((unsigned int)h1 << 16);
    *(unsigned int*)&xl[(size_t)o * 128 + lane * 2] = (unsigned int)l0 | ((unsigned int)l1 << 16);
  }
  *(float2*)&xn[(size_t)o * 128 + lane * 2] = cur;
}

// ------------------------------------------------------------------------
extern "C" void kernel_launch(void* const* d_in, const int* in_sizes, int n_in,
                              void* d_out, int out_size, void* d_ws, size_t ws_size,
                              hipStream_t stream) {
  const float* z        = (const float*)d_in[0];
  const int*   objs     = (const int*)d_in[1];
  const int*   triples  = (const int*)d_in[2];
  const int*   attrs    = (const int*)d_in[3];
  const float* obj_emb  = (const float*)d_in[4];
  const float* attr_emb = (const float*)d_in[5];
  const float* Wrel     = (const float*)d_in[6];
  const float* Wroot    = (const float*)d_in[7];
  const float* bconv    = (const float*)d_in[8];
  const float* box_W1   = (const float*)d_in[9];
  const float* box_b1   = (const float*)d_in[10];
  const float* box_W2   = (const float*)d_in[11];
  const float* box_b2   = (const float*)d_in[12];
  const float* ang_W1   = (const float*)d_in[13];
  const float* ang_b1   = (const float*)d_in[14];
  const float* ang_W2   = (const float*)d_in[15];
  const float* ang_b2   = (const float*)d_in[16];
  float* out = (float*)d_out;

  char* base = (char*)d_ws;
  size_t cur = 0;
  auto alloc = [&](size_t bytes) -> char* {
    char* p = base + cur;
    cur += (bytes + 255) & ~(size_t)255;
    return p;
  };
  float* x0            = (float*)alloc((size_t)NN * 128 * 4);
  float* x1            = (float*)alloc((size_t)NN * 128 * 4);
  unsigned short* Hb   = (unsigned short*)alloc((size_t)NN * 1024 * 2);
  unsigned short* xhi  = (unsigned short*)alloc((size_t)NN * 128 * 2);
  unsigned short* xlo  = (unsigned short*)alloc((size_t)NN * 128 * 2);
  unsigned short* zhi  = (unsigned short*)alloc((size_t)NN * 128 * 2);
  unsigned short* zlo  = (unsigned short*)alloc((size_t)NN * 128 * 2);
  unsigned short* athi = (unsigned short*)alloc((size_t)NN * 32 * 2);
  unsigned short* atlo = (unsigned short*)alloc((size_t)NN * 32 * 2);
  unsigned short* WThi = (unsigned short*)alloc((size_t)LLAY * RREL * 128 * 128 * 2);
  unsigned short* WTlo = (unsigned short*)alloc((size_t)LLAY * RREL * 128 * 128 * 2);
  unsigned short* WrtH = (unsigned short*)alloc((size_t)LLAY * 128 * 128 * 2);
  unsigned short* WrtL = (unsigned short*)alloc((size_t)LLAY * 128 * 128 * 2);
  unsigned short* WcH  = (unsigned short*)alloc((size_t)1024 * 288 * 2);
  unsigned short* WcL  = (unsigned short*)alloc((size_t)1024 * 288 * 2);
  unsigned short* W2H  = (unsigned short*)alloc((size_t)32 * 1024 * 2);
  unsigned short* W2L  = (unsigned short*)alloc((size_t)32 * 1024 * 2);
  float* bcat          = (float*)alloc(1024 * 4);
  float* logits        = (float*)alloc((size_t)NN * 32 * 4);
  int*   cnt      = (int*)alloc((size_t)NBINS * 4);
  int*   binStart = (int*)alloc((size_t)(NBINS + 1) * 4);
  int*   cursor   = (int*)alloc((size_t)NBINS * 4);
  int*   partial  = (int*)alloc(4096);
  int*   offD     = (int*)alloc((size_t)EE * 4);
  float* wD       = (float*)alloc((size_t)EE * 4);

  hipMemsetAsync(cnt, 0, (size_t)NBINS * 4, stream);
  hipMemsetAsync(cursor, 0, (size_t)NBINS * 4, stream);

  build_x0_kernel<<<(NN * 32 + 255) / 256, 256, 0, stream>>>(objs, attrs, obj_emb, attr_emb,
                                                             x0, xhi, xlo);
  prep_zattr<<<(NN * 40 + 255) / 256, 256, 0, stream>>>(z, attrs, attr_emb, zhi, zlo, athi, atlo);
  count_kernel<<<(EE + 255) / 256, 256, 0, stream>>>(triples, cnt);
  const int nPart = (NBINS + 1023) / 1024;
  scanA<<<nPart, 1024, 0, stream>>>(cnt, binStart, partial);
  scanB<<<1, 1024, 0, stream>>>(partial, binStart, nPart);
  scanC<<<nPart, 1024, 0, stream>>>(binStart, partial);
  place_kernel<<<(EE + 255) / 256, 256, 0, stream>>>(triples, cnt, binStart, cursor, offD, wD);
  prep_wrel<<<(LLAY * RREL * 128 * 128 + 255) / 256, 256, 0, stream>>>(Wrel, WThi, WTlo);
  prep_wroot<<<(LLAY * 128 * 128 + 255) / 256, 256, 0, stream>>>(Wroot, WrtH, WrtL);
  prep_wcat<<<(1024 * 288 + 255) / 256, 256, 0, stream>>>(box_W1, ang_W1, WcH, WcL);
  prep_bcat<<<4, 256, 0, stream>>>(box_b1, ang_b1, bcat);
  prep_w2cat<<<(32 * 1024 + 255) / 256, 256, 0, stream>>>(box_W2, ang_W2, W2H, W2L);

  float* xc = x0;
  float* xn = x1;
  const int rowBlocks = (NN + 63) / 64;      // 782
  const int rowBlocks128 = (NN + 127) / 128; // 391
  for (int j = 0; j < LLAY; ++j) {
    root_mfma<<<rowBlocks, 256, 0, stream>>>(xhi, xlo, WrtH + (size_t)j * 128 * 128,
                                             WrtL + (size_t)j * 128 * 128,
                                             bconv + (size_t)j * 128, xn);
    for (int g = 0; g < 2; ++g) {
      const unsigned short* Bh = WThi + ((size_t)j * RREL + g * 8) * 128 * 128;
      const unsigned short* Bl = WTlo + ((size_t)j * RREL + g * 8) * 128 * 128;
      hrel_mfma<<<dim3(8, rowBlocks128), 256, 0, stream>>>(xhi, xlo, Bh, Bl, Hb);
      gather_kernel<<<(NN + 3) / 4, 256, 0, stream>>>(Hb, binStart, offD, wD, xn,
                                                      xhi, xlo, g, (g == 1) ? 1 : 0);
    }
    float* tmp = xc; xc = xn; xn = tmp;
  }

  mlpcat_mfma<<<dim3(8, rowBlocks), 256, 0, stream>>>(xhi, xlo, zhi, zlo, athi, atlo,
                                                      WcH, WcL, bcat, Hb);
  head_mfma<<<(NN + 255) / 256, 256, 0, stream>>>(Hb, W2H, W2L, logits);
  head_post<<<(NN + 255) / 256, 256, 0, stream>>>(logits, box_b2, ang_b2, out);
}